// Round 15
// baseline (143.396 us; speedup 1.0000x reference)
//
#include <hip/hip_runtime.h>
#include <math.h>

#define N_    8
#define C_    256
#define H_    64
#define W_    64
#define HW    4096
#define OUT_  256
#define HEADS 8
#define HD    32
#define K2    9
#define OFFCH 144   // HEADS*K2*2
#define AWCH  72    // HEADS*K2
#define KTOT  2304  // 9 taps * 256 c
#define WPROWS 256  // Wp rows (216 real + zero pad to 256)
#define ABASE 16896 // bf16 offset of B region in conv smem (2*4*66*32)

typedef __bf16 bf16x8 __attribute__((ext_vector_type(8)));
typedef __bf16 bf16x4 __attribute__((ext_vector_type(4)));
typedef float  f32x4  __attribute__((ext_vector_type(4)));

__device__ __forceinline__ void gload_lds16(const void* g, void* l) {
  __builtin_amdgcn_global_load_lds(
      (const __attribute__((address_space(1))) void*)g,
      (__attribute__((address_space(3))) void*)l, 16, 0, 0);
}

// ---------------------------------------------------------------------------
// pack_x: fp32 NCHW -> bf16 NHWC  (xp[n][y][x][c]), LDS 64x64 tile transpose.
// ---------------------------------------------------------------------------
__global__ __launch_bounds__(256) void pack_x_kernel(
    const float* __restrict__ x, __bf16* __restrict__ xp)
{
  const int c0 = blockIdx.x << 6;
  const int y  = blockIdx.y;
  const int n  = blockIdx.z;
  const int tid = threadIdx.x;
  __shared__ float tile[64][65];

  const int tx = tid & 63, tg = tid >> 6;
#pragma unroll
  for (int i = 0; i < 16; ++i) {
    int cl = tg + (i << 2);
    tile[cl][tx] = x[((size_t)(n * C_ + c0 + cl) * H_ + y) * W_ + tx];
  }
  __syncthreads();
#pragma unroll
  for (int i = 0; i < 16; ++i) {
    int xl = tg + (i << 2);
    xp[((size_t)(n * HW) + y * W_ + xl) * C_ + c0 + tx] = (__bf16)tile[tx][xl];
  }
}

// ---------------------------------------------------------------------------
// pack_w: conv weights -> bf16 Wp[256][tap][c] (tap-major K, rows 216+ zero),
// + bias, + zero page for halo DMA.
// ---------------------------------------------------------------------------
__global__ __launch_bounds__(256) void pack_w_kernel(
    const float* __restrict__ off_w, const float* __restrict__ off_b,
    const float* __restrict__ attn_w, const float* __restrict__ attn_b,
    __bf16* __restrict__ Wp, float* __restrict__ biasp,
    __bf16* __restrict__ zbuf)
{
  const int co = blockIdx.x;
  const int c  = threadIdx.x;
  if (co == 0) {  // zero page for OOB halo DMA (4096 B)
    *(uint4*)&zbuf[(size_t)c * 8] = make_uint4(0u, 0u, 0u, 0u);
  }
  const float* base = nullptr;
  if (co < OFFCH)      base = off_w  + ((size_t)co * C_ + c) * 9;
  else if (co < 216)   base = attn_w + ((size_t)(co - OFFCH) * C_ + c) * 9;
#pragma unroll
  for (int t = 0; t < 9; ++t) {
    float w = base ? base[t] : 0.f;
    Wp[(size_t)co * KTOT + t * C_ + c] = (__bf16)w;
  }
  if (c == 0) {
    float b = 0.f;
    if (co < OFFCH) b = off_b[co];
    else if (co < 216) b = attn_b[co - OFFCH];
    biasp[co] = b;
  }
}

// 256x256 fp32 -> bf16 row-major
__global__ __launch_bounds__(256) void pack_mat_kernel(
    const float* __restrict__ Wsrc, __bf16* __restrict__ Wdst)
{
  const int i = blockIdx.x * 256 + threadIdx.x;
  Wdst[i] = (__bf16)Wsrc[i];
}

// ---------------------------------------------------------------------------
// conv_mfma R14: wave-private B pipeline, near-barrier-free.
// Block = 128 spatial (2 image rows) x 128 co (padded); grid (32,2,8)=512.
// Wave = 8 Mtiles x 2 Ntiles = 16 MFMA/tap; wave owns 32 co: stages its own
// B (2 gload_lds/tap, private 2-buf LDS) -> B sync = own vmcnt only.
// A shared (dbuf per c-slice): 1 barrier per slice (9 total).
// LDS 49 KB -> 2 blocks/CU; bank-conflict-free via chunk-XOR source swizzle.
// ---------------------------------------------------------------------------
__global__ __launch_bounds__(256) void conv_mfma_kernel(
    const __bf16* __restrict__ xp, const __bf16* __restrict__ Wp,
    const float* __restrict__ biasp, const __bf16* __restrict__ zbuf,
    __bf16* __restrict__ P2)
{
  const int yt = blockIdx.x;          // 0..31 -> rows y0, y0+1
  const int bn = blockIdx.y;          // co half (0:0..127, 1:128..255)
  const int n  = blockIdx.z;
  const int y0 = yt << 1;
  const int tid = threadIdx.x;
  const int lw = tid & 63, wv = tid >> 6;
  const int lr = lw & 15, lg = lw >> 4;

  // A: 2 bufs x 4 rows x 66 cols x 32 c = 16896 bf16 (33.8 KB)
  // B: 4 waves x 2 bufs x 32 co x 32 c = 8192 bf16 (16 KB)
  __shared__ __align__(16) __bf16 smem[16896 + 8192];

  f32x4 acc[8][2];
#pragma unroll
  for (int m = 0; m < 8; ++m)
#pragma unroll
    for (int nt = 0; nt < 2; ++nt) acc[m][nt] = (f32x4){0.f, 0.f, 0.f, 0.f};

  // zero halo columns 0 and 65 of all 2x4 A rows (written once, never DMA'd)
  if (tid < 64) {
    int p = tid & 3, cs = (tid >> 2) & 1, r = (tid >> 3) & 3, buf = tid >> 5;
    int col = cs ? 65 : 0;
    *(uint4*)&smem[((buf * 4 + r) * 66 + col) * 32 + p * 8] =
        make_uint4(0u, 0u, 0u, 0u);
  }

  const int wB = ABASE + wv * 2048;    // wave's private B region

  auto stage_B = [&](int T) {          // tap T -> wave buf T&1 (2 instr/wave)
    const int ci = T / 9, t = T - ci * 9, pb = T & 1;
    const size_t base = (size_t)(bn * 128 + wv * 32) * KTOT + t * C_ + (ci << 5);
#pragma unroll
    for (int jj = 0; jj < 2; ++jj) {
      const int col = (jj << 4) + (lw >> 2);     // co_local 0..31
      const int cg  = (lw & 3) ^ ((col >> 1) & 3);
      gload_lds16(Wp + base + (size_t)col * KTOT + (cg << 3),
                  &smem[wB + pb * 1024 + (jj << 9)]);
    }
  };
  auto stage_A = [&](int cin) {        // slice cin -> A buf cin&1 (4 instr/wave)
    const int buf = cin & 1, c0 = cin << 5;
#pragma unroll
    for (int k = 0; k < 4; ++k) {      // wave wv stages A row wv, quarter k
      const int y = y0 - 1 + wv;
      const int col = 1 + (k << 4) + (lw >> 2);
      const int cg = (lw & 3) ^ ((col >> 1) & 3);
      const __bf16* src = ((unsigned)y < (unsigned)H_)
          ? xp + ((size_t)(n * HW) + y * W_ + (col - 1)) * C_ + c0 + (cg << 3)
          : zbuf;
      gload_lds16(src, &smem[((buf * 4 + wv) * 66 + 1 + (k << 4)) * 32]);
    }
  };

  // ---- prologue: A(0) [4], B(0) [2]; drain A; barrier ----
  stage_A(0);
  stage_B(0);
  asm volatile("s_waitcnt vmcnt(2)" ::: "memory");   // A(0) done, B(0) in flight
  __builtin_amdgcn_s_barrier();
  asm volatile("" ::: "memory");

  // ---- main loop: 72 flat taps, wave-private pipeline ----
  for (int T = 0; T < 72; ++T) {
    const int ci = T / 9, off = T - ci * 9;
    const int abuf = ci & 1, pb = T & 1;

    if (off == 1 && ci < 7) stage_A(ci + 1);   // A before B: older in queue
    if (T < 71) stage_B(T + 1);

    // gate own B(T) [and A when queued older]
    if (T == 71)                 asm volatile("s_waitcnt vmcnt(0)" ::: "memory");
    else if (off == 1 && ci < 7) asm volatile("s_waitcnt vmcnt(6)" ::: "memory");
    else                         asm volatile("s_waitcnt vmcnt(2)" ::: "memory");

    // ---- 16 MFMAs for tap T ----
    const int dy = off / 3, dxp = off - dy * 3;
    bf16x8 a[8], b[2];
#pragma unroll
    for (int m = 0; m < 8; ++m) {
      const int rr  = (m >> 2) + dy;               // A row 0..3
      const int col = ((m & 3) << 4) + lr + dxp;   // 0..65
      const int p = lg ^ ((col >> 1) & 3);
      a[m] = *(const bf16x8*)&smem[((abuf * 4 + rr) * 66 + col) * 32 + p * 8];
    }
#pragma unroll
    for (int nt = 0; nt < 2; ++nt) {
      const int col = (nt << 4) + lr;              // co_local
      const int p = lg ^ ((col >> 1) & 3);
      b[nt] = *(const bf16x8*)&smem[wB + pb * 1024 + col * 32 + p * 8];
    }
    __builtin_amdgcn_s_setprio(1);
#pragma unroll
    for (int m = 0; m < 8; ++m)
#pragma unroll
      for (int nt = 0; nt < 2; ++nt)
        acc[m][nt] =
            __builtin_amdgcn_mfma_f32_16x16x32_bf16(a[m], b[nt], acc[m][nt], 0, 0, 0);
    __builtin_amdgcn_s_setprio(0);

    // slice boundary: one barrier (A(ci+1) already per-wave drained at off>=2)
    if (off == 8 && T < 71) {
      __builtin_amdgcn_s_barrier();
      asm volatile("" ::: "memory");
    }
  }

  // ---- epilogue: bias (+ sigmoid), head-packed store to P2[n][s][32h+j] ----
#pragma unroll
  for (int nt = 0; nt < 2; ++nt) {
    const int co = bn * 128 + wv * 32 + (nt << 4) + lr;
    if (co < 216) {
      const float bias = biasp[co];
      int idx;
      if (co < OFFCH) {
        int hh = co / 18;
        idx = (hh << 5) + (co - 18 * hh);
      } else {
        int r = co - OFFCH;
        int hh = r / 9;
        idx = (hh << 5) + 18 + (r - 9 * hh);
      }
#pragma unroll
      for (int m = 0; m < 8; ++m) {
#pragma unroll
        for (int reg = 0; reg < 4; ++reg) {
          const int sl = (m << 4) + (lg << 2) + reg;   // 0..127
          const int yout = y0 + (sl >> 6), xo = sl & 63;
          float v = acc[m][nt][reg] + bias;
          if (co >= OFFCH) v = 1.f / (1.f + expf(-v));
          P2[((size_t)n * HW + yout * W_ + xo) * 256 + idx] = (__bf16)v;
        }
      }
    }
  }
}

// ---------------------------------------------------------------------------
// gemm256: D[n][s][co] = sum_c A[n][s][c]*Wb[co][c]
// MODE 0: store bf16 NHWC (vproj -> vtb). MODE 1: store fp32 NCHW (wo -> out).
// ---------------------------------------------------------------------------
template <int MODE>
__global__ __launch_bounds__(256) void gemm256_kernel(
    const __bf16* __restrict__ A, const __bf16* __restrict__ Wb,
    __bf16* __restrict__ out_b, float* __restrict__ out_f)
{
  const int st = blockIdx.x;
  const int bn = blockIdx.y;
  const int n  = blockIdx.z;
  const int s0 = st << 7;
  const int tid = threadIdx.x;

  __shared__ __bf16 Asl[128][40];
  __shared__ __bf16 Bsl[128][40];

  const int lw = tid & 63, wv = tid >> 6;
  const int lr = lw & 15, lg = lw >> 4;
  const int sm_base = wv << 5;

  f32x4 acc[2][8];
#pragma unroll
  for (int m = 0; m < 2; ++m)
#pragma unroll
    for (int nt = 0; nt < 8; ++nt) acc[m][nt] = (f32x4){0.f, 0.f, 0.f, 0.f};

  for (int c0 = 0; c0 < 256; c0 += 32) {
    __syncthreads();
#pragma unroll
    for (int it = 0; it < 2; ++it) {
      int i = tid + (it << 8);
      int cg = i & 3, r = i >> 2;
      *(uint4*)&Asl[r][cg << 3] =
          *(const uint4*)&A[((size_t)n * HW + s0 + r) * 256 + c0 + (cg << 3)];
    }
#pragma unroll
    for (int it = 0; it < 2; ++it) {
      int i = tid + (it << 8);
      int cg = i & 3, r = i >> 2;
      *(uint4*)&Bsl[r][cg << 3] =
          *(const uint4*)&Wb[(size_t)((bn << 7) + r) * 256 + c0 + (cg << 3)];
    }
    __syncthreads();

    bf16x8 a0 = *(const bf16x8*)&Asl[sm_base + lr][lg << 3];
    bf16x8 a1 = *(const bf16x8*)&Asl[sm_base + 16 + lr][lg << 3];
#pragma unroll
    for (int nt = 0; nt < 8; ++nt) {
      bf16x8 b = *(const bf16x8*)&Bsl[(nt << 4) + lr][lg << 3];
      acc[0][nt] = __builtin_amdgcn_mfma_f32_16x16x32_bf16(a0, b, acc[0][nt], 0, 0, 0);
      acc[1][nt] = __builtin_amdgcn_mfma_f32_16x16x32_bf16(a1, b, acc[1][nt], 0, 0, 0);
    }
  }

#pragma unroll
  for (int m = 0; m < 2; ++m) {
#pragma unroll
    for (int nt = 0; nt < 8; ++nt) {
      const int co = (bn << 7) + (nt << 4) + lr;
      if (MODE == 0) {
#pragma unroll
        for (int reg = 0; reg < 4; ++reg) {
          const int sm = sm_base + (m << 4) + (lg << 2) + reg;
          out_b[((size_t)n * HW + s0 + sm) * 256 + co] = (__bf16)acc[m][nt][reg];
        }
      } else {
        const int sm = sm_base + (m << 4) + (lg << 2);
        float4 v4 = make_float4(acc[m][nt][0], acc[m][nt][1],
                                acc[m][nt][2], acc[m][nt][3]);
        *(float4*)&out_f[((size_t)(n * 256 + co)) * HW + s0 + sm] = v4;
      }
    }
  }
}

// ---------------------------------------------------------------------------
// Deformable sampling: 4 lanes per (n,h,s), 8 channels each (bf16x8).
// P params read as 4 vector loads from head-packed P2 (27 contiguous bf16).
// ---------------------------------------------------------------------------
__global__ __launch_bounds__(256) void sample_kernel(
    const __bf16* __restrict__ vtb, const __bf16* __restrict__ P2,
    __bf16* __restrict__ comb)
{
  const int gid = blockIdx.x * 256 + threadIdx.x;
  const int cg  = gid & 3;        // channel oct within head
  const int q   = gid >> 2;       // point index
  const int s = q & (HW - 1);
  const int h = (q >> 12) & (HEADS - 1);
  const int n = q >> 15;
  const int yq = s >> 6, xq = s & 63;

  const __bf16* prow = P2 + ((size_t)n * HW + s) * 256 + (h << 5);
  bf16x8 p0 = *(const bf16x8*)(prow);       // pairs k=0..3
  bf16x8 p1 = *(const bf16x8*)(prow + 8);   // pairs k=4..7
  bf16x8 p2 = *(const bf16x8*)(prow + 16);  // pair k=8; aw k=0..5
  bf16x4 p3 = *(const bf16x4*)(prow + 24);  // aw k=6..8

  float acc[8];
#pragma unroll
  for (int j = 0; j < 8; ++j) acc[j] = 0.f;

  const __bf16* vbase = vtb + ((size_t)n * HW) * 256 + (h << 5) + (cg << 3);

#pragma unroll
  for (int k = 0; k < K2; ++k) {
    float offx, offy, a;
    if (k < 4)      { offx = (float)p0[2 * k];       offy = (float)p0[2 * k + 1]; }
    else if (k < 8) { offx = (float)p1[2 * (k - 4)]; offy = (float)p1[2 * (k - 4) + 1]; }
    else            { offx = (float)p2[0];           offy = (float)p2[1]; }
    if (k < 6)      a = (float)p2[2 + k];
    else            a = (float)p3[k - 6];

    const float xpf = (float)xq + offx * (63.f / 64.f);
    const float ypf = (float)yq + offy * (63.f / 64.f);
    const float fx0 = floorf(xpf), fy0 = floorf(ypf);
    const int x0 = (int)fx0, y0 = (int)fy0;
    const float wx1 = xpf - fx0, wx0 = 1.f - wx1;
    const float wy1 = ypf - fy0, wy0 = 1.f - wy1;

#pragma unroll
    for (int cy = 0; cy < 2; ++cy) {
      const int yi = y0 + cy;
      if ((unsigned)yi >= (unsigned)H_) continue;
      const float wy = cy ? wy1 : wy0;
#pragma unroll
      for (int cx = 0; cx < 2; ++cx) {
        const int xi = x0 + cx;
        if ((unsigned)xi >= (unsigned)W_) continue;
        const float cw = a * wy * (cx ? wx1 : wx0);
        bf16x8 v = *(const bf16x8*)(vbase + (size_t)(yi * W_ + xi) * 256);
#pragma unroll
        for (int j = 0; j < 8; ++j) acc[j] = fmaf(cw, (float)v[j], acc[j]);
      }
    }
  }

  bf16x8 r;
#pragma unroll
  for (int j = 0; j < 8; ++j) r[j] = (__bf16)acc[j];
  *(bf16x8*)&comb[((size_t)n * HW + s) * 256 + (h << 5) + (cg << 3)] = r;
}

// ---------------------------------------------------------------------------
extern "C" void kernel_launch(void* const* d_in, const int* in_sizes, int n_in,
                              void* d_out, int out_size, void* d_ws,
                              size_t ws_size, hipStream_t stream)
{
  const float* x      = (const float*)d_in[0];
  // d_in[1] = Wq, d_in[2] = Wk : dead code (q,k unused in reference)
  const float* Wv     = (const float*)d_in[3];
  const float* off_w  = (const float*)d_in[4];
  const float* off_b  = (const float*)d_in[5];
  const float* attn_w = (const float*)d_in[6];
  const float* attn_b = (const float*)d_in[7];
  const float* Wo     = (const float*)d_in[8];
  float* out = (float*)d_out;

  __bf16* vtb   = (__bf16*)d_ws;                         // 16.78 MB
  __bf16* xp    = vtb + (size_t)N_ * HW * OUT_;          // 16.78 MB
  __bf16* comb  = xp + (size_t)N_ * HW * C_;             // 16.78 MB
  __bf16* P2    = comb + (size_t)N_ * HW * OUT_;         // 16.78 MB (head-packed)
  __bf16* Wp    = P2 + (size_t)N_ * HW * 256;            //  1.18 MB (256 rows)
  __bf16* Wvb   = Wp + (size_t)WPROWS * KTOT;            //  128 KB
  __bf16* Wob   = Wvb + (size_t)OUT_ * C_;               //  128 KB
  __bf16* zbuf  = Wob + (size_t)OUT_ * OUT_;             //  4 KB zero page
  float*  biasp = (float*)(zbuf + 2048);                 //  1 KB

  pack_w_kernel<<<dim3(256), 256, 0, stream>>>(off_w, off_b, attn_w, attn_b,
                                               Wp, biasp, zbuf);
  pack_mat_kernel<<<dim3(256), 256, 0, stream>>>(Wv, Wvb);
  pack_mat_kernel<<<dim3(256), 256, 0, stream>>>(Wo, Wob);
  pack_x_kernel<<<dim3(4, 64, N_), 256, 0, stream>>>(x, xp);
  conv_mfma_kernel<<<dim3(32, 2, N_), 256, 0, stream>>>(xp, Wp, biasp, zbuf, P2);
  gemm256_kernel<0><<<dim3(32, 2, N_), 256, 0, stream>>>(xp, Wvb, vtb, nullptr);
  sample_kernel<<<dim3((N_ * HEADS * HW * 4) / 256), 256, 0, stream>>>(vtb, P2,
                                                                       comb);
  gemm256_kernel<1><<<dim3(32, 2, N_), 256, 0, stream>>>(comb, Wob, nullptr,
                                                         out);
}

// Round 17
// 134.775 us; speedup vs baseline: 1.0640x; 1.0640x over previous
//
#include <hip/hip_runtime.h>
#include <math.h>

#define N_    8
#define C_    256
#define H_    64
#define W_    64
#define HW    4096
#define OUT_  256
#define HEADS 8
#define HD    32
#define K2    9
#define OFFCH 144   // HEADS*K2*2
#define AWCH  72    // HEADS*K2
#define KTOT  2304  // 9 taps * 256 c
#define WPROWS 256  // Wp rows (216 real + zero pad to 256)
#define ABASE 16896 // bf16 offset of B region in conv smem (2*4*66*32)

typedef __bf16 bf16x8 __attribute__((ext_vector_type(8)));
typedef __bf16 bf16x4 __attribute__((ext_vector_type(4)));
typedef float  f32x4  __attribute__((ext_vector_type(4)));

__device__ __forceinline__ void gload_lds16(const void* g, void* l) {
  __builtin_amdgcn_global_load_lds(
      (const __attribute__((address_space(1))) void*)g,
      (__attribute__((address_space(3))) void*)l, 16, 0, 0);
}

// ---------------------------------------------------------------------------
// pack_x: fp32 NCHW -> bf16 NHWC  (xp[n][y][x][c]), LDS 64x64 tile transpose.
// ---------------------------------------------------------------------------
__global__ __launch_bounds__(256) void pack_x_kernel(
    const float* __restrict__ x, __bf16* __restrict__ xp)
{
  const int c0 = blockIdx.x << 6;
  const int y  = blockIdx.y;
  const int n  = blockIdx.z;
  const int tid = threadIdx.x;
  __shared__ float tile[64][65];

  const int tx = tid & 63, tg = tid >> 6;
#pragma unroll
  for (int i = 0; i < 16; ++i) {
    int cl = tg + (i << 2);
    tile[cl][tx] = x[((size_t)(n * C_ + c0 + cl) * H_ + y) * W_ + tx];
  }
  __syncthreads();
#pragma unroll
  for (int i = 0; i < 16; ++i) {
    int xl = tg + (i << 2);
    xp[((size_t)(n * HW) + y * W_ + xl) * C_ + c0 + tx] = (__bf16)tile[tx][xl];
  }
}

// ---------------------------------------------------------------------------
// pack_w: conv weights -> bf16 Wp[256][tap][c] (tap-major K, rows 216+ zero),
// + bias, + zero page for halo DMA.
// ---------------------------------------------------------------------------
__global__ __launch_bounds__(256) void pack_w_kernel(
    const float* __restrict__ off_w, const float* __restrict__ off_b,
    const float* __restrict__ attn_w, const float* __restrict__ attn_b,
    __bf16* __restrict__ Wp, float* __restrict__ biasp,
    __bf16* __restrict__ zbuf)
{
  const int co = blockIdx.x;
  const int c  = threadIdx.x;
  if (co == 0) {  // zero page for OOB halo DMA (4096 B)
    *(uint4*)&zbuf[(size_t)c * 8] = make_uint4(0u, 0u, 0u, 0u);
  }
  const float* base = nullptr;
  if (co < OFFCH)      base = off_w  + ((size_t)co * C_ + c) * 9;
  else if (co < 216)   base = attn_w + ((size_t)(co - OFFCH) * C_ + c) * 9;
#pragma unroll
  for (int t = 0; t < 9; ++t) {
    float w = base ? base[t] : 0.f;
    Wp[(size_t)co * KTOT + t * C_ + c] = (__bf16)w;
  }
  if (c == 0) {
    float b = 0.f;
    if (co < OFFCH) b = off_b[co];
    else if (co < 216) b = attn_b[co - OFFCH];
    biasp[co] = b;
  }
}

// 256x256 fp32 -> bf16 row-major
__global__ __launch_bounds__(256) void pack_mat_kernel(
    const float* __restrict__ Wsrc, __bf16* __restrict__ Wdst)
{
  const int i = blockIdx.x * 256 + threadIdx.x;
  Wdst[i] = (__bf16)Wsrc[i];
}

// ---------------------------------------------------------------------------
// conv_mfma R16: R14 wave-private structure + hoisted addresses + 18-tap
// unrolled body (abuf/dy/dxp/pb compile-time -> ds_read base+imm, zero
// per-tap VALU addr math, cross-tap compiler scheduling).
// Block = 128 spatial x 128 co (padded); grid (32,2,8)=512, 2 blk/CU.
// ---------------------------------------------------------------------------
__global__ __launch_bounds__(256) void conv_mfma_kernel(
    const __bf16* __restrict__ xp, const __bf16* __restrict__ Wp,
    const float* __restrict__ biasp, const __bf16* __restrict__ zbuf,
    __bf16* __restrict__ P2)
{
  const int yt = blockIdx.x;          // 0..31 -> rows y0, y0+1
  const int bn = blockIdx.y;          // co half (0:0..127, 1:128..255)
  const int n  = blockIdx.z;
  const int y0 = yt << 1;
  const int tid = threadIdx.x;
  const int lw = tid & 63, wv = tid >> 6;
  const int lr = lw & 15, lg = lw >> 4;

  // A: 2 bufs x 4 rows x 66 cols x 32 c = 16896 bf16; B: 4w x 2buf x 32co x 32c
  __shared__ __align__(16) __bf16 smem[16896 + 8192];

  f32x4 acc[8][2];
#pragma unroll
  for (int m = 0; m < 8; ++m)
#pragma unroll
    for (int nt = 0; nt < 2; ++nt) acc[m][nt] = (f32x4){0.f, 0.f, 0.f, 0.f};

  // zero halo columns 0 and 65 of all 2x4 A rows
  if (tid < 64) {
    int p = tid & 3, cs = (tid >> 2) & 1, r = (tid >> 3) & 3, buf = tid >> 5;
    int col = cs ? 65 : 0;
    *(uint4*)&smem[((buf * 4 + r) * 66 + col) * 32 + p * 8] =
        make_uint4(0u, 0u, 0u, 0u);
  }

  // ---- hoisted LDS read offsets (elements; swizzle math once) ----
  int aoff[3][4];
#pragma unroll
  for (int d = 0; d < 3; ++d)
#pragma unroll
    for (int mm = 0; mm < 4; ++mm) {
      int col = (mm << 4) + lr + d;
      int p = lg ^ ((col >> 1) & 3);
      aoff[d][mm] = col * 32 + p * 8;       // row 0, buf 0 base
    }
  int boff[2];
#pragma unroll
  for (int nt = 0; nt < 2; ++nt) {
    int col = (nt << 4) + lr;
    int p = lg ^ ((col >> 1) & 3);
    boff[nt] = ABASE + wv * 2048 + col * 32 + p * 8;   // pb 0 base
  }

  // ---- hoisted global source pointers ----
  const int scg = lw & 3;
  const __bf16* gB[2];
#pragma unroll
  for (int jj = 0; jj < 2; ++jj) {
    int col = (jj << 4) + (lw >> 2);
    int cg = scg ^ ((col >> 1) & 3);
    gB[jj] = Wp + (size_t)(bn * 128 + wv * 32 + col) * KTOT + (cg << 3);
  }
  const __bf16* gA[4];
  int aAdd;                           // per-slice element add (0 if halo row)
  {
    int y = y0 - 1 + wv;
    bool valid = ((unsigned)y < (unsigned)H_);
    aAdd = valid ? 1 : 0;
#pragma unroll
    for (int k = 0; k < 4; ++k) {
      int col = 1 + (k << 4) + (lw >> 2);
      int cg = scg ^ ((col >> 1) & 3);
      gA[k] = valid
          ? xp + ((size_t)(n * HW) + y * W_ + (col - 1)) * C_ + (cg << 3)
          : zbuf;
    }
  }

  auto stageB = [&](int elemOff, int pb) {   // elemOff = t*C_ + ci*32
#pragma unroll
    for (int jj = 0; jj < 2; ++jj)
      gload_lds16(gB[jj] + elemOff,
                  &smem[ABASE + wv * 2048 + pb * 1024 + (jj << 9)]);
  };
  auto stageA = [&](int c0elem, int buf) {
    const int add = aAdd ? c0elem : 0;
#pragma unroll
    for (int k = 0; k < 4; ++k)
      gload_lds16(gA[k] + add,
                  &smem[((buf * 4 + wv) * 66 + 1 + (k << 4)) * 32]);
  };

  // ---- prologue: A(0), B(0); drain A; barrier ----
  stageA(0, 0);
  stageB(0, 0);
  asm volatile("s_waitcnt vmcnt(2)" ::: "memory");
  __builtin_amdgcn_s_barrier();
  asm volatile("" ::: "memory");

  // ---- main loop: 4 x (2 slices x 9 taps, unrolled) ----
  for (int cc = 0; cc < 4; ++cc) {
    const bool lastcc = (cc == 3);
#pragma unroll
    for (int sub = 0; sub < 2; ++sub) {
      const int ci = (cc << 1) + sub;          // runtime
      const int abuf = sub;                    // compile-time
#pragma unroll
      for (int tt = 0; tt < 9; ++tt) {
        const int dy = tt / 3, dxp = tt - dy * 3;   // compile-time
        const int pb = (sub + tt) & 1;              // compile-time
        const bool lastSlice = lastcc && (sub == 1);

        // stage next A / next B; choose wait
        if (tt == 1) {
          if (ci < 7) {
            stageA((ci + 1) << 5, sub ^ 1);
            stageB(2 * C_ + (ci << 5), (sub + 2) & 1);
            asm volatile("s_waitcnt vmcnt(6)" ::: "memory");
          } else {
            stageB(2 * C_ + (ci << 5), (sub + 2) & 1);
            asm volatile("s_waitcnt vmcnt(2)" ::: "memory");
          }
        } else if (tt == 8) {
          if (!lastSlice) {
            stageB(0 * C_ + ((ci + 1) << 5), (sub + 9) & 1);
            asm volatile("s_waitcnt vmcnt(2)" ::: "memory");
          } else {
            asm volatile("s_waitcnt vmcnt(0)" ::: "memory");
          }
        } else {
          stageB((tt + 1) * C_ + (ci << 5), (sub + tt + 1) & 1);
          asm volatile("s_waitcnt vmcnt(2)" ::: "memory");
        }

        // ---- 16 MFMAs for this tap (all LDS offsets are imm-folded) ----
        bf16x8 a[8], b[2];
#pragma unroll
        for (int m = 0; m < 8; ++m) {
          const int rr = (m >> 2) + dy;
          a[m] = *(const bf16x8*)&smem[aoff[dxp][m & 3] +
                                       (abuf * 4 + rr) * 2112];
        }
#pragma unroll
        for (int nt = 0; nt < 2; ++nt)
          b[nt] = *(const bf16x8*)&smem[boff[nt] + (pb << 10)];

        __builtin_amdgcn_s_setprio(1);
#pragma unroll
        for (int m = 0; m < 8; ++m)
#pragma unroll
          for (int nt = 0; nt < 2; ++nt)
            acc[m][nt] = __builtin_amdgcn_mfma_f32_16x16x32_bf16(
                a[m], b[nt], acc[m][nt], 0, 0, 0);
        __builtin_amdgcn_s_setprio(0);

        // slice boundary barrier (A dbuf visibility across waves)
        if (tt == 8 && !lastSlice) {
          __builtin_amdgcn_s_barrier();
          asm volatile("" ::: "memory");
        }
      }
    }
  }

  // ---- epilogue: bias (+ sigmoid), head-packed store to P2[n][s][32h+j] ----
#pragma unroll
  for (int nt = 0; nt < 2; ++nt) {
    const int co = bn * 128 + wv * 32 + (nt << 4) + lr;
    if (co < 216) {
      const float bias = biasp[co];
      int idx;
      if (co < OFFCH) {
        int hh = co / 18;
        idx = (hh << 5) + (co - 18 * hh);
      } else {
        int r = co - OFFCH;
        int hh = r / 9;
        idx = (hh << 5) + 18 + (r - 9 * hh);
      }
#pragma unroll
      for (int m = 0; m < 8; ++m) {
#pragma unroll
        for (int reg = 0; reg < 4; ++reg) {
          const int sl = (m << 4) + (lg << 2) + reg;   // 0..127
          const int yout = y0 + (sl >> 6), xo = sl & 63;
          float v = acc[m][nt][reg] + bias;
          if (co >= OFFCH) v = 1.f / (1.f + expf(-v));
          P2[((size_t)n * HW + yout * W_ + xo) * 256 + idx] = (__bf16)v;
        }
      }
    }
  }
}

// ---------------------------------------------------------------------------
// gemm256: D[n][s][co] = sum_c A[n][s][c]*Wb[co][c]
// MODE 0: store bf16 NHWC (vproj -> vtb). MODE 1: store fp32 NCHW (wo -> out).
// ---------------------------------------------------------------------------
template <int MODE>
__global__ __launch_bounds__(256) void gemm256_kernel(
    const __bf16* __restrict__ A, const __bf16* __restrict__ Wb,
    __bf16* __restrict__ out_b, float* __restrict__ out_f)
{
  const int st = blockIdx.x;
  const int bn = blockIdx.y;
  const int n  = blockIdx.z;
  const int s0 = st << 7;
  const int tid = threadIdx.x;

  __shared__ __bf16 Asl[128][40];
  __shared__ __bf16 Bsl[128][40];

  const int lw = tid & 63, wv = tid >> 6;
  const int lr = lw & 15, lg = lw >> 4;
  const int sm_base = wv << 5;

  f32x4 acc[2][8];
#pragma unroll
  for (int m = 0; m < 2; ++m)
#pragma unroll
    for (int nt = 0; nt < 8; ++nt) acc[m][nt] = (f32x4){0.f, 0.f, 0.f, 0.f};

  for (int c0 = 0; c0 < 256; c0 += 32) {
    __syncthreads();
#pragma unroll
    for (int it = 0; it < 2; ++it) {
      int i = tid + (it << 8);
      int cg = i & 3, r = i >> 2;
      *(uint4*)&Asl[r][cg << 3] =
          *(const uint4*)&A[((size_t)n * HW + s0 + r) * 256 + c0 + (cg << 3)];
    }
#pragma unroll
    for (int it = 0; it < 2; ++it) {
      int i = tid + (it << 8);
      int cg = i & 3, r = i >> 2;
      *(uint4*)&Bsl[r][cg << 3] =
          *(const uint4*)&Wb[(size_t)((bn << 7) + r) * 256 + c0 + (cg << 3)];
    }
    __syncthreads();

    bf16x8 a0 = *(const bf16x8*)&Asl[sm_base + lr][lg << 3];
    bf16x8 a1 = *(const bf16x8*)&Asl[sm_base + 16 + lr][lg << 3];
#pragma unroll
    for (int nt = 0; nt < 8; ++nt) {
      bf16x8 b = *(const bf16x8*)&Bsl[(nt << 4) + lr][lg << 3];
      acc[0][nt] = __builtin_amdgcn_mfma_f32_16x16x32_bf16(a0, b, acc[0][nt], 0, 0, 0);
      acc[1][nt] = __builtin_amdgcn_mfma_f32_16x16x32_bf16(a1, b, acc[1][nt], 0, 0, 0);
    }
  }

#pragma unroll
  for (int m = 0; m < 2; ++m) {
#pragma unroll
    for (int nt = 0; nt < 8; ++nt) {
      const int co = (bn << 7) + (nt << 4) + lr;
      if (MODE == 0) {
#pragma unroll
        for (int reg = 0; reg < 4; ++reg) {
          const int sm = sm_base + (m << 4) + (lg << 2) + reg;
          out_b[((size_t)n * HW + s0 + sm) * 256 + co] = (__bf16)acc[m][nt][reg];
        }
      } else {
        const int sm = sm_base + (m << 4) + (lg << 2);
        float4 v4 = make_float4(acc[m][nt][0], acc[m][nt][1],
                                acc[m][nt][2], acc[m][nt][3]);
        *(float4*)&out_f[((size_t)(n * 256 + co)) * HW + s0 + sm] = v4;
      }
    }
  }
}

// ---------------------------------------------------------------------------
// Deformable sampling: 4 lanes per (n,h,s), 8 channels each (bf16x8).
// ---------------------------------------------------------------------------
__global__ __launch_bounds__(256) void sample_kernel(
    const __bf16* __restrict__ vtb, const __bf16* __restrict__ P2,
    __bf16* __restrict__ comb)
{
  const int gid = blockIdx.x * 256 + threadIdx.x;
  const int cg  = gid & 3;        // channel oct within head
  const int q   = gid >> 2;       // point index
  const int s = q & (HW - 1);
  const int h = (q >> 12) & (HEADS - 1);
  const int n = q >> 15;
  const int yq = s >> 6, xq = s & 63;

  const __bf16* prow = P2 + ((size_t)n * HW + s) * 256 + (h << 5);
  bf16x8 p0 = *(const bf16x8*)(prow);       // pairs k=0..3
  bf16x8 p1 = *(const bf16x8*)(prow + 8);   // pairs k=4..7
  bf16x8 p2 = *(const bf16x8*)(prow + 16);  // pair k=8; aw k=0..5
  bf16x4 p3 = *(const bf16x4*)(prow + 24);  // aw k=6..8

  float acc[8];
#pragma unroll
  for (int j = 0; j < 8; ++j) acc[j] = 0.f;

  const __bf16* vbase = vtb + ((size_t)n * HW) * 256 + (h << 5) + (cg << 3);

#pragma unroll
  for (int k = 0; k < K2; ++k) {
    float offx, offy, a;
    if (k < 4)      { offx = (float)p0[2 * k];       offy = (float)p0[2 * k + 1]; }
    else if (k < 8) { offx = (float)p1[2 * (k - 4)]; offy = (float)p1[2 * (k - 4) + 1]; }
    else            { offx = (float)p2[0];           offy = (float)p2[1]; }
    if (k < 6)      a = (float)p2[2 + k];
    else            a = (float)p3[k - 6];

    const float xpf = (float)xq + offx * (63.f / 64.f);
    const float ypf = (float)yq + offy * (63.f / 64.f);
    const float fx0 = floorf(xpf), fy0 = floorf(ypf);
    const int x0 = (int)fx0, y0 = (int)fy0;
    const float wx1 = xpf - fx0, wx0 = 1.f - wx1;
    const float wy1 = ypf - fy0, wy0 = 1.f - wy1;

#pragma unroll
    for (int cy = 0; cy < 2; ++cy) {
      const int yi = y0 + cy;
      if ((unsigned)yi >= (unsigned)H_) continue;
      const float wy = cy ? wy1 : wy0;
#pragma unroll
      for (int cx = 0; cx < 2; ++cx) {
        const int xi = x0 + cx;
        if ((unsigned)xi >= (unsigned)W_) continue;
        const float cw = a * wy * (cx ? wx1 : wx0);
        bf16x8 v = *(const bf16x8*)(vbase + (size_t)(yi * W_ + xi) * 256);
#pragma unroll
        for (int j = 0; j < 8; ++j) acc[j] = fmaf(cw, (float)v[j], acc[j]);
      }
    }
  }

  bf16x8 r;
#pragma unroll
  for (int j = 0; j < 8; ++j) r[j] = (__bf16)acc[j];
  *(bf16x8*)&comb[((size_t)n * HW + s) * 256 + (h << 5) + (cg << 3)] = r;
}

// ---------------------------------------------------------------------------
extern "C" void kernel_launch(void* const* d_in, const int* in_sizes, int n_in,
                              void* d_out, int out_size, void* d_ws,
                              size_t ws_size, hipStream_t stream)
{
  const float* x      = (const float*)d_in[0];
  // d_in[1] = Wq, d_in[2] = Wk : dead code (q,k unused in reference)
  const float* Wv     = (const float*)d_in[3];
  const float* off_w  = (const float*)d_in[4];
  const float* off_b  = (const float*)d_in[5];
  const float* attn_w = (const float*)d_in[6];
  const float* attn_b = (const float*)d_in[7];
  const float* Wo     = (const float*)d_in[8];
  float* out = (float*)d_out;

  __bf16* vtb   = (__bf16*)d_ws;                         // 16.78 MB
  __bf16* xp    = vtb + (size_t)N_ * HW * OUT_;          // 16.78 MB
  __bf16* comb  = xp + (size_t)N_ * HW * C_;             // 16.78 MB
  __bf16* P2    = comb + (size_t)N_ * HW * OUT_;         // 16.78 MB (head-packed)
  __bf16* Wp    = P2 + (size_t)N_ * HW * 256;            //  1.18 MB (256 rows)
  __bf16* Wvb   = Wp + (size_t)WPROWS * KTOT;            //  128 KB
  __bf16* Wob   = Wvb + (size_t)OUT_ * C_;               //  128 KB
  __bf16* zbuf  = Wob + (size_t)OUT_ * OUT_;             //  4 KB zero page
  float*  biasp = (float*)(zbuf + 2048);                 //  1 KB

  pack_w_kernel<<<dim3(256), 256, 0, stream>>>(off_w, off_b, attn_w, attn_b,
                                               Wp, biasp, zbuf);
  pack_mat_kernel<<<dim3(256), 256, 0, stream>>>(Wv, Wvb);
  pack_mat_kernel<<<dim3(256), 256, 0, stream>>>(Wo, Wob);
  pack_x_kernel<<<dim3(4, 64, N_), 256, 0, stream>>>(x, xp);
  conv_mfma_kernel<<<dim3(32, 2, N_), 256, 0, stream>>>(xp, Wp, biasp, zbuf, P2);
  gemm256_kernel<0><<<dim3(32, 2, N_), 256, 0, stream>>>(xp, Wvb, vtb, nullptr);
  sample_kernel<<<dim3((N_ * HEADS * HW * 4) / 256), 256, 0, stream>>>(vtb, P2,
                                                                       comb);
  gemm256_kernel<1><<<dim3(32, 2, N_), 256, 0, stream>>>(comb, Wob, nullptr,
                                                         out);
}

// Round 20
// 124.697 us; speedup vs baseline: 1.1500x; 1.0808x over previous
//
#include <hip/hip_runtime.h>
#include <math.h>

#define N_    8
#define C_    256
#define H_    64
#define W_    64
#define HW    4096
#define OUT_  256
#define HEADS 8
#define HD    32
#define K2    9
#define OFFCH 144   // HEADS*K2*2
#define AWCH  72    // HEADS*K2
#define KTOT  2304  // 9 taps * 256 c
#define WPROWS 256  // Wp rows (216 real + zero pad to 256)
#define ABASE 16896 // bf16 offset of B region in conv smem (2*4*66*32)

typedef __bf16 bf16x8 __attribute__((ext_vector_type(8)));
typedef __bf16 bf16x4 __attribute__((ext_vector_type(4)));
typedef float  f32x4  __attribute__((ext_vector_type(4)));

__device__ __forceinline__ void gload_lds16(const void* g, void* l) {
  __builtin_amdgcn_global_load_lds(
      (const __attribute__((address_space(1))) void*)g,
      (__attribute__((address_space(3))) void*)l, 16, 0, 0);
}

// ---------------------------------------------------------------------------
// pack_x: fp32 NCHW -> bf16 NHWC  (xp[n][y][x][c]), LDS 64x64 tile transpose.
// ---------------------------------------------------------------------------
__global__ __launch_bounds__(256) void pack_x_kernel(
    const float* __restrict__ x, __bf16* __restrict__ xp)
{
  const int c0 = blockIdx.x << 6;
  const int y  = blockIdx.y;
  const int n  = blockIdx.z;
  const int tid = threadIdx.x;
  __shared__ float tile[64][65];

  const int tx = tid & 63, tg = tid >> 6;
#pragma unroll
  for (int i = 0; i < 16; ++i) {
    int cl = tg + (i << 2);
    tile[cl][tx] = x[((size_t)(n * C_ + c0 + cl) * H_ + y) * W_ + tx];
  }
  __syncthreads();
#pragma unroll
  for (int i = 0; i < 16; ++i) {
    int xl = tg + (i << 2);
    xp[((size_t)(n * HW) + y * W_ + xl) * C_ + c0 + tx] = (__bf16)tile[tx][xl];
  }
}

// ---------------------------------------------------------------------------
// pack_w: conv weights -> bf16 Wp[256][tap][c] (tap-major K, rows 216+ zero),
// + bias, + zero page for halo DMA.
// ---------------------------------------------------------------------------
__global__ __launch_bounds__(256) void pack_w_kernel(
    const float* __restrict__ off_w, const float* __restrict__ off_b,
    const float* __restrict__ attn_w, const float* __restrict__ attn_b,
    __bf16* __restrict__ Wp, float* __restrict__ biasp,
    __bf16* __restrict__ zbuf)
{
  const int co = blockIdx.x;
  const int c  = threadIdx.x;
  if (co == 0) {  // zero page for OOB halo DMA (4096 B)
    *(uint4*)&zbuf[(size_t)c * 8] = make_uint4(0u, 0u, 0u, 0u);
  }
  const float* base = nullptr;
  if (co < OFFCH)      base = off_w  + ((size_t)co * C_ + c) * 9;
  else if (co < 216)   base = attn_w + ((size_t)(co - OFFCH) * C_ + c) * 9;
#pragma unroll
  for (int t = 0; t < 9; ++t) {
    float w = base ? base[t] : 0.f;
    Wp[(size_t)co * KTOT + t * C_ + c] = (__bf16)w;
  }
  if (c == 0) {
    float b = 0.f;
    if (co < OFFCH) b = off_b[co];
    else if (co < 216) b = attn_b[co - OFFCH];
    biasp[co] = b;
  }
}

// 256x256 fp32 -> bf16 row-major
__global__ __launch_bounds__(256) void pack_mat_kernel(
    const float* __restrict__ Wsrc, __bf16* __restrict__ Wdst)
{
  const int i = blockIdx.x * 256 + threadIdx.x;
  Wdst[i] = (__bf16)Wsrc[i];
}

// ---------------------------------------------------------------------------
// conv_mfma R16 (unchanged): wave-private B pipeline + hoisted addresses +
// 18-tap unrolled body. Block = 128 spatial x 128 co; grid (32,2,8)=512.
// ---------------------------------------------------------------------------
__global__ __launch_bounds__(256) void conv_mfma_kernel(
    const __bf16* __restrict__ xp, const __bf16* __restrict__ Wp,
    const float* __restrict__ biasp, const __bf16* __restrict__ zbuf,
    __bf16* __restrict__ P2)
{
  const int yt = blockIdx.x;          // 0..31 -> rows y0, y0+1
  const int bn = blockIdx.y;          // co half (0:0..127, 1:128..255)
  const int n  = blockIdx.z;
  const int y0 = yt << 1;
  const int tid = threadIdx.x;
  const int lw = tid & 63, wv = tid >> 6;
  const int lr = lw & 15, lg = lw >> 4;

  __shared__ __align__(16) __bf16 smem[16896 + 8192];

  f32x4 acc[8][2];
#pragma unroll
  for (int m = 0; m < 8; ++m)
#pragma unroll
    for (int nt = 0; nt < 2; ++nt) acc[m][nt] = (f32x4){0.f, 0.f, 0.f, 0.f};

  if (tid < 64) {
    int p = tid & 3, cs = (tid >> 2) & 1, r = (tid >> 3) & 3, buf = tid >> 5;
    int col = cs ? 65 : 0;
    *(uint4*)&smem[((buf * 4 + r) * 66 + col) * 32 + p * 8] =
        make_uint4(0u, 0u, 0u, 0u);
  }

  int aoff[3][4];
#pragma unroll
  for (int d = 0; d < 3; ++d)
#pragma unroll
    for (int mm = 0; mm < 4; ++mm) {
      int col = (mm << 4) + lr + d;
      int p = lg ^ ((col >> 1) & 3);
      aoff[d][mm] = col * 32 + p * 8;
    }
  int boff[2];
#pragma unroll
  for (int nt = 0; nt < 2; ++nt) {
    int col = (nt << 4) + lr;
    int p = lg ^ ((col >> 1) & 3);
    boff[nt] = ABASE + wv * 2048 + col * 32 + p * 8;
  }

  const int scg = lw & 3;
  const __bf16* gB[2];
#pragma unroll
  for (int jj = 0; jj < 2; ++jj) {
    int col = (jj << 4) + (lw >> 2);
    int cg = scg ^ ((col >> 1) & 3);
    gB[jj] = Wp + (size_t)(bn * 128 + wv * 32 + col) * KTOT + (cg << 3);
  }
  const __bf16* gA[4];
  int aAdd;
  {
    int y = y0 - 1 + wv;
    bool valid = ((unsigned)y < (unsigned)H_);
    aAdd = valid ? 1 : 0;
#pragma unroll
    for (int k = 0; k < 4; ++k) {
      int col = 1 + (k << 4) + (lw >> 2);
      int cg = scg ^ ((col >> 1) & 3);
      gA[k] = valid
          ? xp + ((size_t)(n * HW) + y * W_ + (col - 1)) * C_ + (cg << 3)
          : zbuf;
    }
  }

  auto stageB = [&](int elemOff, int pb) {
#pragma unroll
    for (int jj = 0; jj < 2; ++jj)
      gload_lds16(gB[jj] + elemOff,
                  &smem[ABASE + wv * 2048 + pb * 1024 + (jj << 9)]);
  };
  auto stageA = [&](int c0elem, int buf) {
    const int add = aAdd ? c0elem : 0;
#pragma unroll
    for (int k = 0; k < 4; ++k)
      gload_lds16(gA[k] + add,
                  &smem[((buf * 4 + wv) * 66 + 1 + (k << 4)) * 32]);
  };

  stageA(0, 0);
  stageB(0, 0);
  asm volatile("s_waitcnt vmcnt(2)" ::: "memory");
  __builtin_amdgcn_s_barrier();
  asm volatile("" ::: "memory");

  for (int cc = 0; cc < 4; ++cc) {
    const bool lastcc = (cc == 3);
#pragma unroll
    for (int sub = 0; sub < 2; ++sub) {
      const int ci = (cc << 1) + sub;
      const int abuf = sub;
#pragma unroll
      for (int tt = 0; tt < 9; ++tt) {
        const int dy = tt / 3, dxp = tt - dy * 3;
        const int pb = (sub + tt) & 1;
        const bool lastSlice = lastcc && (sub == 1);

        if (tt == 1) {
          if (ci < 7) {
            stageA((ci + 1) << 5, sub ^ 1);
            stageB(2 * C_ + (ci << 5), (sub + 2) & 1);
            asm volatile("s_waitcnt vmcnt(6)" ::: "memory");
          } else {
            stageB(2 * C_ + (ci << 5), (sub + 2) & 1);
            asm volatile("s_waitcnt vmcnt(2)" ::: "memory");
          }
        } else if (tt == 8) {
          if (!lastSlice) {
            stageB(0 * C_ + ((ci + 1) << 5), (sub + 9) & 1);
            asm volatile("s_waitcnt vmcnt(2)" ::: "memory");
          } else {
            asm volatile("s_waitcnt vmcnt(0)" ::: "memory");
          }
        } else {
          stageB((tt + 1) * C_ + (ci << 5), (sub + tt + 1) & 1);
          asm volatile("s_waitcnt vmcnt(2)" ::: "memory");
        }

        bf16x8 a[8], b[2];
#pragma unroll
        for (int m = 0; m < 8; ++m) {
          const int rr = (m >> 2) + dy;
          a[m] = *(const bf16x8*)&smem[aoff[dxp][m & 3] +
                                       (abuf * 4 + rr) * 2112];
        }
#pragma unroll
        for (int nt = 0; nt < 2; ++nt)
          b[nt] = *(const bf16x8*)&smem[boff[nt] + (pb << 10)];

        __builtin_amdgcn_s_setprio(1);
#pragma unroll
        for (int m = 0; m < 8; ++m)
#pragma unroll
          for (int nt = 0; nt < 2; ++nt)
            acc[m][nt] = __builtin_amdgcn_mfma_f32_16x16x32_bf16(
                a[m], b[nt], acc[m][nt], 0, 0, 0);
        __builtin_amdgcn_s_setprio(0);

        if (tt == 8 && !lastSlice) {
          __builtin_amdgcn_s_barrier();
          asm volatile("" ::: "memory");
        }
      }
    }
  }

#pragma unroll
  for (int nt = 0; nt < 2; ++nt) {
    const int co = bn * 128 + wv * 32 + (nt << 4) + lr;
    if (co < 216) {
      const float bias = biasp[co];
      int idx;
      if (co < OFFCH) {
        int hh = co / 18;
        idx = (hh << 5) + (co - 18 * hh);
      } else {
        int r = co - OFFCH;
        int hh = r / 9;
        idx = (hh << 5) + 18 + (r - 9 * hh);
      }
#pragma unroll
      for (int m = 0; m < 8; ++m) {
#pragma unroll
        for (int reg = 0; reg < 4; ++reg) {
          const int sl = (m << 4) + (lg << 2) + reg;
          const int yout = y0 + (sl >> 6), xo = sl & 63;
          float v = acc[m][nt][reg] + bias;
          if (co >= OFFCH) v = 1.f / (1.f + expf(-v));
          P2[((size_t)n * HW + yout * W_ + xo) * 256 + idx] = (__bf16)v;
        }
      }
    }
  }
}

// ---------------------------------------------------------------------------
// gemm256: D[n][s][co] = sum_c A[n][s][c]*Wb[co][c]
// MODE 0: store bf16 NHWC (vproj -> vtb). MODE 1: store fp32 NCHW (wo -> out).
// ---------------------------------------------------------------------------
template <int MODE>
__global__ __launch_bounds__(256) void gemm256_kernel(
    const __bf16* __restrict__ A, const __bf16* __restrict__ Wb,
    __bf16* __restrict__ out_b, float* __restrict__ out_f)
{
  const int st = blockIdx.x;
  const int bn = blockIdx.y;
  const int n  = blockIdx.z;
  const int s0 = st << 7;
  const int tid = threadIdx.x;

  __shared__ __bf16 Asl[128][40];
  __shared__ __bf16 Bsl[128][40];

  const int lw = tid & 63, wv = tid >> 6;
  const int lr = lw & 15, lg = lw >> 4;
  const int sm_base = wv << 5;

  f32x4 acc[2][8];
#pragma unroll
  for (int m = 0; m < 2; ++m)
#pragma unroll
    for (int nt = 0; nt < 8; ++nt) acc[m][nt] = (f32x4){0.f, 0.f, 0.f, 0.f};

  for (int c0 = 0; c0 < 256; c0 += 32) {
    __syncthreads();
#pragma unroll
    for (int it = 0; it < 2; ++it) {
      int i = tid + (it << 8);
      int cg = i & 3, r = i >> 2;
      *(uint4*)&Asl[r][cg << 3] =
          *(const uint4*)&A[((size_t)n * HW + s0 + r) * 256 + c0 + (cg << 3)];
    }
#pragma unroll
    for (int it = 0; it < 2; ++it) {
      int i = tid + (it << 8);
      int cg = i & 3, r = i >> 2;
      *(uint4*)&Bsl[r][cg << 3] =
          *(const uint4*)&Wb[(size_t)((bn << 7) + r) * 256 + c0 + (cg << 3)];
    }
    __syncthreads();

    bf16x8 a0 = *(const bf16x8*)&Asl[sm_base + lr][lg << 3];
    bf16x8 a1 = *(const bf16x8*)&Asl[sm_base + 16 + lr][lg << 3];
#pragma unroll
    for (int nt = 0; nt < 8; ++nt) {
      bf16x8 b = *(const bf16x8*)&Bsl[(nt << 4) + lr][lg << 3];
      acc[0][nt] = __builtin_amdgcn_mfma_f32_16x16x32_bf16(a0, b, acc[0][nt], 0, 0, 0);
      acc[1][nt] = __builtin_amdgcn_mfma_f32_16x16x32_bf16(a1, b, acc[1][nt], 0, 0, 0);
    }
  }

#pragma unroll
  for (int m = 0; m < 2; ++m) {
#pragma unroll
    for (int nt = 0; nt < 8; ++nt) {
      const int co = (bn << 7) + (nt << 4) + lr;
      if (MODE == 0) {
#pragma unroll
        for (int reg = 0; reg < 4; ++reg) {
          const int sm = sm_base + (m << 4) + (lg << 2) + reg;
          out_b[((size_t)n * HW + s0 + sm) * 256 + co] = (__bf16)acc[m][nt][reg];
        }
      } else {
        const int sm = sm_base + (m << 4) + (lg << 2);
        float4 v4 = make_float4(acc[m][nt][0], acc[m][nt][1],
                                acc[m][nt][2], acc[m][nt][3]);
        *(float4*)&out_f[((size_t)(n * 256 + co)) * HW + s0 + sm] = v4;
      }
    }
  }
}

// ---------------------------------------------------------------------------
// Deformable sampling R18: LDS-windowed gather.
// Block ↔ (n,h,y): stage rows y-3..y+4 of this head's 32 ch (32 KB LDS);
// 36 corner gathers per point become ds_read_b128; rare out-of-window
// corners (|offy|>~3, >=6-sigma) fall back to global (exact correctness).
// Thread = (xq, cg): 4 lanes per point, 8 ch each.
// ---------------------------------------------------------------------------
__global__ __launch_bounds__(256) void sample_kernel(
    const __bf16* __restrict__ vtb, const __bf16* __restrict__ P2,
    __bf16* __restrict__ comb)
{
  const int b = blockIdx.x;           // (n*8 + h)*64 + y
  const int y = b & 63;
  const int h = (b >> 6) & 7;
  const int n = b >> 9;
  const int tid = threadIdx.x;
  const int xq = tid >> 2, cg = tid & 3;
  const int lw = tid & 63, wv = tid >> 6;

  __shared__ __align__(16) __bf16 vsl[8 * 64 * 32];   // [r][x][cho] 32 KB

  // ---- stage window rows (invalid rows skipped; never read) ----
  const int xs = (wv << 4) + (lw >> 2);
  const int cs = lw & 3;
  const __bf16* vrow0 =
      vtb + ((size_t)n * HW) * 256 + (h << 5) + (cs << 3) + (size_t)xs * 256;
#pragma unroll
  for (int r = 0; r < 8; ++r) {
    int yy = y - 3 + r;
    if ((unsigned)yy < (unsigned)H_)            // block-uniform branch
      gload_lds16(vrow0 + (size_t)yy * (64 * 256),
                  &vsl[(r * 64 + (wv << 4)) * 32]);
  }

  // P2 params (independent of staging)
  const __bf16* prow = P2 + ((size_t)n * HW + y * 64 + xq) * 256 + (h << 5);
  bf16x8 p0 = *(const bf16x8*)(prow);
  bf16x8 p1 = *(const bf16x8*)(prow + 8);
  bf16x8 p2 = *(const bf16x8*)(prow + 16);
  bf16x4 p3 = *(const bf16x4*)(prow + 24);

  __syncthreads();                               // drains vmcnt (gload_lds)

  float acc[8];
#pragma unroll
  for (int j = 0; j < 8; ++j) acc[j] = 0.f;

  const __bf16* vbase = vtb + ((size_t)n * HW) * 256 + (h << 5) + (cg << 3);

#pragma unroll
  for (int k = 0; k < K2; ++k) {
    float offx, offy, a;
    if (k < 4)      { offx = (float)p0[2 * k];       offy = (float)p0[2 * k + 1]; }
    else if (k < 8) { offx = (float)p1[2 * (k - 4)]; offy = (float)p1[2 * (k - 4) + 1]; }
    else            { offx = (float)p2[0];           offy = (float)p2[1]; }
    if (k < 6)      a = (float)p2[2 + k];
    else            a = (float)p3[k - 6];

    const float xpf = (float)xq + offx * (63.f / 64.f);
    const float ypf = (float)y  + offy * (63.f / 64.f);
    const float fx0 = floorf(xpf), fy0 = floorf(ypf);
    const int x0 = (int)fx0, y0 = (int)fy0;
    const float wx1 = xpf - fx0, wx0 = 1.f - wx1;
    const float wy1 = ypf - fy0, wy0 = 1.f - wy1;

#pragma unroll
    for (int cy = 0; cy < 2; ++cy) {
      const int yi = y0 + cy;
      if ((unsigned)yi >= (unsigned)H_) continue;
      const float wy = cy ? wy1 : wy0;
      const int ridx = yi - (y - 3);
#pragma unroll
      for (int cx = 0; cx < 2; ++cx) {
        const int xi = x0 + cx;
        if ((unsigned)xi >= (unsigned)W_) continue;
        const float cw = a * wy * (cx ? wx1 : wx0);
        bf16x8 v;
        if ((unsigned)ridx < 8u) {               // in-window: LDS
          v = *(const bf16x8*)&vsl[(ridx * 64 + xi) * 32 + (cg << 3)];
        } else {                                 // rare escape: global
          v = *(const bf16x8*)(vbase + (size_t)(yi * W_ + xi) * 256);
        }
#pragma unroll
        for (int j = 0; j < 8; ++j) acc[j] = fmaf(cw, (float)v[j], acc[j]);
      }
    }
  }

  bf16x8 r;
#pragma unroll
  for (int j = 0; j < 8; ++j) r[j] = (__bf16)acc[j];
  *(bf16x8*)&comb[((size_t)n * HW + y * 64 + xq) * 256 + (h << 5) + (cg << 3)] = r;
}

// ---------------------------------------------------------------------------
extern "C" void kernel_launch(void* const* d_in, const int* in_sizes, int n_in,
                              void* d_out, int out_size, void* d_ws,
                              size_t ws_size, hipStream_t stream)
{
  const float* x      = (const float*)d_in[0];
  // d_in[1] = Wq, d_in[2] = Wk : dead code (q,k unused in reference)
  const float* Wv     = (const float*)d_in[3];
  const float* off_w  = (const float*)d_in[4];
  const float* off_b  = (const float*)d_in[5];
  const float* attn_w = (const float*)d_in[6];
  const float* attn_b = (const float*)d_in[7];
  const float* Wo     = (const float*)d_in[8];
  float* out = (float*)d_out;

  __bf16* vtb   = (__bf16*)d_ws;                         // 16.78 MB
  __bf16* xp    = vtb + (size_t)N_ * HW * OUT_;          // 16.78 MB
  __bf16* comb  = xp + (size_t)N_ * HW * C_;             // 16.78 MB
  __bf16* P2    = comb + (size_t)N_ * HW * OUT_;         // 16.78 MB (head-packed)
  __bf16* Wp    = P2 + (size_t)N_ * HW * 256;            //  1.18 MB (256 rows)
  __bf16* Wvb   = Wp + (size_t)WPROWS * KTOT;            //  128 KB
  __bf16* Wob   = Wvb + (size_t)OUT_ * C_;               //  128 KB
  __bf16* zbuf  = Wob + (size_t)OUT_ * OUT_;             //  4 KB zero page
  float*  biasp = (float*)(zbuf + 2048);                 //  1 KB

  pack_w_kernel<<<dim3(256), 256, 0, stream>>>(off_w, off_b, attn_w, attn_b,
                                               Wp, biasp, zbuf);
  pack_mat_kernel<<<dim3(256), 256, 0, stream>>>(Wv, Wvb);
  pack_mat_kernel<<<dim3(256), 256, 0, stream>>>(Wo, Wob);
  pack_x_kernel<<<dim3(4, 64, N_), 256, 0, stream>>>(x, xp);
  conv_mfma_kernel<<<dim3(32, 2, N_), 256, 0, stream>>>(xp, Wp, biasp, zbuf, P2);
  gemm256_kernel<0><<<dim3(32, 2, N_), 256, 0, stream>>>(xp, Wvb, vtb, nullptr);
  sample_kernel<<<dim3(N_ * HEADS * H_), 256, 0, stream>>>(vtb, P2, comb);
  gemm256_kernel<1><<<dim3(32, 2, N_), 256, 0, stream>>>(comb, Wob, nullptr,
                                                         out);
}

// Round 21
// 124.408 us; speedup vs baseline: 1.1526x; 1.0023x over previous
//
#include <hip/hip_runtime.h>
#include <math.h>

#define N_    8
#define C_    256
#define H_    64
#define W_    64
#define HW    4096
#define OUT_  256
#define HEADS 8
#define HD    32
#define K2    9
#define OFFCH 144   // HEADS*K2*2
#define AWCH  72    // HEADS*K2
#define KTOT  2304  // 9 taps * 256 c
#define WPROWS 256  // Wp rows (216 real + zero pad to 256)
#define ABASE 16896 // bf16 offset of B region in conv smem (2*4*66*32)

typedef __bf16 bf16x8 __attribute__((ext_vector_type(8)));
typedef __bf16 bf16x4 __attribute__((ext_vector_type(4)));
typedef float  f32x4  __attribute__((ext_vector_type(4)));

__device__ __forceinline__ void gload_lds16(const void* g, void* l) {
  __builtin_amdgcn_global_load_lds(
      (const __attribute__((address_space(1))) void*)g,
      (__attribute__((address_space(3))) void*)l, 16, 0, 0);
}

// ---------------------------------------------------------------------------
// pack_x: fp32 NCHW -> bf16 NHWC  (xp[n][y][x][c]), LDS 64x64 tile transpose.
// ---------------------------------------------------------------------------
__global__ __launch_bounds__(256) void pack_x_kernel(
    const float* __restrict__ x, __bf16* __restrict__ xp)
{
  const int c0 = blockIdx.x << 6;
  const int y  = blockIdx.y;
  const int n  = blockIdx.z;
  const int tid = threadIdx.x;
  __shared__ float tile[64][65];

  const int tx = tid & 63, tg = tid >> 6;
#pragma unroll
  for (int i = 0; i < 16; ++i) {
    int cl = tg + (i << 2);
    tile[cl][tx] = x[((size_t)(n * C_ + c0 + cl) * H_ + y) * W_ + tx];
  }
  __syncthreads();
#pragma unroll
  for (int i = 0; i < 16; ++i) {
    int xl = tg + (i << 2);
    xp[((size_t)(n * HW) + y * W_ + xl) * C_ + c0 + tx] = (__bf16)tile[tx][xl];
  }
}

// ---------------------------------------------------------------------------
// pack_w: conv weights -> bf16 Wp[256][tap][c] (tap-major K, rows 216+ zero),
// + bias, + zero page for halo DMA.
// ---------------------------------------------------------------------------
__global__ __launch_bounds__(256) void pack_w_kernel(
    const float* __restrict__ off_w, const float* __restrict__ off_b,
    const float* __restrict__ attn_w, const float* __restrict__ attn_b,
    __bf16* __restrict__ Wp, float* __restrict__ biasp,
    __bf16* __restrict__ zbuf)
{
  const int co = blockIdx.x;
  const int c  = threadIdx.x;
  if (co == 0) {  // zero page for OOB halo DMA (4096 B)
    *(uint4*)&zbuf[(size_t)c * 8] = make_uint4(0u, 0u, 0u, 0u);
  }
  const float* base = nullptr;
  if (co < OFFCH)      base = off_w  + ((size_t)co * C_ + c) * 9;
  else if (co < 216)   base = attn_w + ((size_t)(co - OFFCH) * C_ + c) * 9;
#pragma unroll
  for (int t = 0; t < 9; ++t) {
    float w = base ? base[t] : 0.f;
    Wp[(size_t)co * KTOT + t * C_ + c] = (__bf16)w;
  }
  if (c == 0) {
    float b = 0.f;
    if (co < OFFCH) b = off_b[co];
    else if (co < 216) b = attn_b[co - OFFCH];
    biasp[co] = b;
  }
}

// 256x256 fp32 -> bf16 row-major
__global__ __launch_bounds__(256) void pack_mat_kernel(
    const float* __restrict__ Wsrc, __bf16* __restrict__ Wdst)
{
  const int i = blockIdx.x * 256 + threadIdx.x;
  Wdst[i] = (__bf16)Wsrc[i];
}

// ---------------------------------------------------------------------------
// conv_mfma R21: R16 structure + B prefetch depth 2 (3 rotating wave-private
// buffers; T%3 == tt%3 so buffer indices stay compile-time in the unrolled
// body). vmcnt gates: 8 at tt in {1,2} (A+2B younger), 4 steady, 2/0 taper.
// Block = 128 spatial x 128 co; grid (32,2,8)=512; LDS 58.4 KB -> 2 blk/CU.
// ---------------------------------------------------------------------------
__global__ __launch_bounds__(256) void conv_mfma_kernel(
    const __bf16* __restrict__ xp, const __bf16* __restrict__ Wp,
    const float* __restrict__ biasp, const __bf16* __restrict__ zbuf,
    __bf16* __restrict__ P2)
{
  const int yt = blockIdx.x;          // 0..31 -> rows y0, y0+1
  const int bn = blockIdx.y;          // co half (0:0..127, 1:128..255)
  const int n  = blockIdx.z;
  const int y0 = yt << 1;
  const int tid = threadIdx.x;
  const int lw = tid & 63, wv = tid >> 6;
  const int lr = lw & 15, lg = lw >> 4;

  // A: 2 bufs x 4 rows x 66 cols x 32 c = 16896 bf16
  // B: 4 waves x 3 bufs x 32 co x 32 c = 12288 bf16
  __shared__ __align__(16) __bf16 smem[16896 + 12288];

  f32x4 acc[8][2];
#pragma unroll
  for (int m = 0; m < 8; ++m)
#pragma unroll
    for (int nt = 0; nt < 2; ++nt) acc[m][nt] = (f32x4){0.f, 0.f, 0.f, 0.f};

  // zero halo columns 0 and 65 of all 2x4 A rows
  if (tid < 64) {
    int p = tid & 3, cs = (tid >> 2) & 1, r = (tid >> 3) & 3, buf = tid >> 5;
    int col = cs ? 65 : 0;
    *(uint4*)&smem[((buf * 4 + r) * 66 + col) * 32 + p * 8] =
        make_uint4(0u, 0u, 0u, 0u);
  }

  // ---- hoisted LDS read offsets ----
  int aoff[3][4];
#pragma unroll
  for (int d = 0; d < 3; ++d)
#pragma unroll
    for (int mm = 0; mm < 4; ++mm) {
      int col = (mm << 4) + lr + d;
      int p = lg ^ ((col >> 1) & 3);
      aoff[d][mm] = col * 32 + p * 8;
    }
  int boff[2];
#pragma unroll
  for (int nt = 0; nt < 2; ++nt) {
    int col = (nt << 4) + lr;
    int p = lg ^ ((col >> 1) & 3);
    boff[nt] = ABASE + wv * 3072 + col * 32 + p * 8;   // buf 0 base
  }

  // ---- hoisted global source pointers ----
  const int scg = lw & 3;
  const __bf16* gB[2];
#pragma unroll
  for (int jj = 0; jj < 2; ++jj) {
    int col = (jj << 4) + (lw >> 2);
    int cg = scg ^ ((col >> 1) & 3);
    gB[jj] = Wp + (size_t)(bn * 128 + wv * 32 + col) * KTOT + (cg << 3);
  }
  const __bf16* gA[4];
  int aAdd;
  {
    int y = y0 - 1 + wv;
    bool valid = ((unsigned)y < (unsigned)H_);
    aAdd = valid ? 1 : 0;
#pragma unroll
    for (int k = 0; k < 4; ++k) {
      int col = 1 + (k << 4) + (lw >> 2);
      int cg = scg ^ ((col >> 1) & 3);
      gA[k] = valid
          ? xp + ((size_t)(n * HW) + y * W_ + (col - 1)) * C_ + (cg << 3)
          : zbuf;
    }
  }

  auto stageB = [&](int elemOff, int pbuf) {
#pragma unroll
    for (int jj = 0; jj < 2; ++jj)
      gload_lds16(gB[jj] + elemOff,
                  &smem[ABASE + wv * 3072 + pbuf * 1024 + (jj << 9)]);
  };
  auto stageA = [&](int c0elem, int buf) {
    const int add = aAdd ? c0elem : 0;
#pragma unroll
    for (int k = 0; k < 4; ++k)
      gload_lds16(gA[k] + add,
                  &smem[((buf * 4 + wv) * 66 + 1 + (k << 4)) * 32]);
  };

  // ---- prologue: A(0)[4], B(0)->buf0, B(1)->buf1; A drained; barrier ----
  stageA(0, 0);
  stageB(0 * C_ + 0, 0);
  stageB(1 * C_ + 0, 1);
  asm volatile("s_waitcnt vmcnt(4)" ::: "memory");   // A(0) done
  __builtin_amdgcn_s_barrier();
  asm volatile("" ::: "memory");

  // ---- main loop: 4 x (2 slices x 9 taps, unrolled); B staged 2 ahead ----
  for (int cc = 0; cc < 4; ++cc) {
    const bool lastcc = (cc == 3);
#pragma unroll
    for (int sub = 0; sub < 2; ++sub) {
      const int ci = (cc << 1) + sub;          // runtime
      const int abuf = sub;                    // compile-time
#pragma unroll
      for (int tt = 0; tt < 9; ++tt) {
        const int dy = tt / 3, dxp = tt - dy * 3;   // compile-time
        const int pbR = tt % 3;                     // compile-time read buf
        const int pbW = (tt + 2) % 3;               // compile-time write buf
        const bool lastSlice = lastcc && (sub == 1);

        if (tt == 1 && ci < 7) stageA((ci + 1) << 5, sub ^ 1);

        if (!(lastSlice && tt >= 7)) {              // issue B(T+2)
          const int tn  = (tt < 7) ? (tt + 2) : (tt - 7);
          const int cin = (tt < 7) ? ci : (ci + 1);
          stageB(tn * C_ + (cin << 5), pbW);
        }

        // gate B(T): count loads younger than B(T)'s pair
        if (lastSlice && tt == 8)
          asm volatile("s_waitcnt vmcnt(0)" ::: "memory");
        else if (lastSlice && tt == 7)
          asm volatile("s_waitcnt vmcnt(2)" ::: "memory");
        else if ((tt == 1 || tt == 2) && ci < 7)
          asm volatile("s_waitcnt vmcnt(8)" ::: "memory");
        else
          asm volatile("s_waitcnt vmcnt(4)" ::: "memory");

        // ---- 16 MFMAs for this tap (imm-folded LDS offsets) ----
        bf16x8 a[8], b[2];
#pragma unroll
        for (int m = 0; m < 8; ++m) {
          const int rr = (m >> 2) + dy;
          a[m] = *(const bf16x8*)&smem[aoff[dxp][m & 3] +
                                       (abuf * 4 + rr) * 2112];
        }
#pragma unroll
        for (int nt = 0; nt < 2; ++nt)
          b[nt] = *(const bf16x8*)&smem[boff[nt] + (pbR << 10)];

        __builtin_amdgcn_s_setprio(1);
#pragma unroll
        for (int m = 0; m < 8; ++m)
#pragma unroll
          for (int nt = 0; nt < 2; ++nt)
            acc[m][nt] = __builtin_amdgcn_mfma_f32_16x16x32_bf16(
                a[m], b[nt], acc[m][nt], 0, 0, 0);
        __builtin_amdgcn_s_setprio(0);

        // slice boundary barrier (A dbuf visibility across waves)
        if (tt == 8 && !lastSlice) {
          __builtin_amdgcn_s_barrier();
          asm volatile("" ::: "memory");
        }
      }
    }
  }

  // ---- epilogue: bias (+ sigmoid), head-packed store to P2[n][s][32h+j] ----
#pragma unroll
  for (int nt = 0; nt < 2; ++nt) {
    const int co = bn * 128 + wv * 32 + (nt << 4) + lr;
    if (co < 216) {
      const float bias = biasp[co];
      int idx;
      if (co < OFFCH) {
        int hh = co / 18;
        idx = (hh << 5) + (co - 18 * hh);
      } else {
        int r = co - OFFCH;
        int hh = r / 9;
        idx = (hh << 5) + 18 + (r - 9 * hh);
      }
#pragma unroll
      for (int m = 0; m < 8; ++m) {
#pragma unroll
        for (int reg = 0; reg < 4; ++reg) {
          const int sl = (m << 4) + (lg << 2) + reg;   // 0..127
          const int yout = y0 + (sl >> 6), xo = sl & 63;
          float v = acc[m][nt][reg] + bias;
          if (co >= OFFCH) v = 1.f / (1.f + expf(-v));
          P2[((size_t)n * HW + yout * W_ + xo) * 256 + idx] = (__bf16)v;
        }
      }
    }
  }
}

// ---------------------------------------------------------------------------
// gemm256: D[n][s][co] = sum_c A[n][s][c]*Wb[co][c]
// MODE 0: store bf16 NHWC (vproj -> vtb). MODE 1: store fp32 NCHW (wo -> out).
// ---------------------------------------------------------------------------
template <int MODE>
__global__ __launch_bounds__(256) void gemm256_kernel(
    const __bf16* __restrict__ A, const __bf16* __restrict__ Wb,
    __bf16* __restrict__ out_b, float* __restrict__ out_f)
{
  const int st = blockIdx.x;
  const int bn = blockIdx.y;
  const int n  = blockIdx.z;
  const int s0 = st << 7;
  const int tid = threadIdx.x;

  __shared__ __bf16 Asl[128][40];
  __shared__ __bf16 Bsl[128][40];

  const int lw = tid & 63, wv = tid >> 6;
  const int lr = lw & 15, lg = lw >> 4;
  const int sm_base = wv << 5;

  f32x4 acc[2][8];
#pragma unroll
  for (int m = 0; m < 2; ++m)
#pragma unroll
    for (int nt = 0; nt < 8; ++nt) acc[m][nt] = (f32x4){0.f, 0.f, 0.f, 0.f};

  for (int c0 = 0; c0 < 256; c0 += 32) {
    __syncthreads();
#pragma unroll
    for (int it = 0; it < 2; ++it) {
      int i = tid + (it << 8);
      int cg = i & 3, r = i >> 2;
      *(uint4*)&Asl[r][cg << 3] =
          *(const uint4*)&A[((size_t)n * HW + s0 + r) * 256 + c0 + (cg << 3)];
    }
#pragma unroll
    for (int it = 0; it < 2; ++it) {
      int i = tid + (it << 8);
      int cg = i & 3, r = i >> 2;
      *(uint4*)&Bsl[r][cg << 3] =
          *(const uint4*)&Wb[(size_t)((bn << 7) + r) * 256 + c0 + (cg << 3)];
    }
    __syncthreads();

    bf16x8 a0 = *(const bf16x8*)&Asl[sm_base + lr][lg << 3];
    bf16x8 a1 = *(const bf16x8*)&Asl[sm_base + 16 + lr][lg << 3];
#pragma unroll
    for (int nt = 0; nt < 8; ++nt) {
      bf16x8 b = *(const bf16x8*)&Bsl[(nt << 4) + lr][lg << 3];
      acc[0][nt] = __builtin_amdgcn_mfma_f32_16x16x32_bf16(a0, b, acc[0][nt], 0, 0, 0);
      acc[1][nt] = __builtin_amdgcn_mfma_f32_16x16x32_bf16(a1, b, acc[1][nt], 0, 0, 0);
    }
  }

#pragma unroll
  for (int m = 0; m < 2; ++m) {
#pragma unroll
    for (int nt = 0; nt < 8; ++nt) {
      const int co = (bn << 7) + (nt << 4) + lr;
      if (MODE == 0) {
#pragma unroll
        for (int reg = 0; reg < 4; ++reg) {
          const int sm = sm_base + (m << 4) + (lg << 2) + reg;
          out_b[((size_t)n * HW + s0 + sm) * 256 + co] = (__bf16)acc[m][nt][reg];
        }
      } else {
        const int sm = sm_base + (m << 4) + (lg << 2);
        float4 v4 = make_float4(acc[m][nt][0], acc[m][nt][1],
                                acc[m][nt][2], acc[m][nt][3]);
        *(float4*)&out_f[((size_t)(n * 256 + co)) * HW + s0 + sm] = v4;
      }
    }
  }
}

// ---------------------------------------------------------------------------
// Deformable sampling R18 (unchanged): LDS-windowed gather.
// ---------------------------------------------------------------------------
__global__ __launch_bounds__(256) void sample_kernel(
    const __bf16* __restrict__ vtb, const __bf16* __restrict__ P2,
    __bf16* __restrict__ comb)
{
  const int b = blockIdx.x;           // (n*8 + h)*64 + y
  const int y = b & 63;
  const int h = (b >> 6) & 7;
  const int n = b >> 9;
  const int tid = threadIdx.x;
  const int xq = tid >> 2, cg = tid & 3;
  const int lw = tid & 63, wv = tid >> 6;

  __shared__ __align__(16) __bf16 vsl[8 * 64 * 32];   // [r][x][cho] 32 KB

  const int xs = (wv << 4) + (lw >> 2);
  const int cs = lw & 3;
  const __bf16* vrow0 =
      vtb + ((size_t)n * HW) * 256 + (h << 5) + (cs << 3) + (size_t)xs * 256;
#pragma unroll
  for (int r = 0; r < 8; ++r) {
    int yy = y - 3 + r;
    if ((unsigned)yy < (unsigned)H_)            // block-uniform branch
      gload_lds16(vrow0 + (size_t)yy * (64 * 256),
                  &vsl[(r * 64 + (wv << 4)) * 32]);
  }

  const __bf16* prow = P2 + ((size_t)n * HW + y * 64 + xq) * 256 + (h << 5);
  bf16x8 p0 = *(const bf16x8*)(prow);
  bf16x8 p1 = *(const bf16x8*)(prow + 8);
  bf16x8 p2 = *(const bf16x8*)(prow + 16);
  bf16x4 p3 = *(const bf16x4*)(prow + 24);

  __syncthreads();                               // drains vmcnt (gload_lds)

  float acc[8];
#pragma unroll
  for (int j = 0; j < 8; ++j) acc[j] = 0.f;

  const __bf16* vbase = vtb + ((size_t)n * HW) * 256 + (h << 5) + (cg << 3);

#pragma unroll
  for (int k = 0; k < K2; ++k) {
    float offx, offy, a;
    if (k < 4)      { offx = (float)p0[2 * k];       offy = (float)p0[2 * k + 1]; }
    else if (k < 8) { offx = (float)p1[2 * (k - 4)]; offy = (float)p1[2 * (k - 4) + 1]; }
    else            { offx = (float)p2[0];           offy = (float)p2[1]; }
    if (k < 6)      a = (float)p2[2 + k];
    else            a = (float)p3[k - 6];

    const float xpf = (float)xq + offx * (63.f / 64.f);
    const float ypf = (float)y  + offy * (63.f / 64.f);
    const float fx0 = floorf(xpf), fy0 = floorf(ypf);
    const int x0 = (int)fx0, y0 = (int)fy0;
    const float wx1 = xpf - fx0, wx0 = 1.f - wx1;
    const float wy1 = ypf - fy0, wy0 = 1.f - wy1;

#pragma unroll
    for (int cy = 0; cy < 2; ++cy) {
      const int yi = y0 + cy;
      if ((unsigned)yi >= (unsigned)H_) continue;
      const float wy = cy ? wy1 : wy0;
      const int ridx = yi - (y - 3);
#pragma unroll
      for (int cx = 0; cx < 2; ++cx) {
        const int xi = x0 + cx;
        if ((unsigned)xi >= (unsigned)W_) continue;
        const float cw = a * wy * (cx ? wx1 : wx0);
        bf16x8 v;
        if ((unsigned)ridx < 8u) {               // in-window: LDS
          v = *(const bf16x8*)&vsl[(ridx * 64 + xi) * 32 + (cg << 3)];
        } else {                                 // rare escape: global
          v = *(const bf16x8*)(vbase + (size_t)(yi * W_ + xi) * 256);
        }
#pragma unroll
        for (int j = 0; j < 8; ++j) acc[j] = fmaf(cw, (float)v[j], acc[j]);
      }
    }
  }

  bf16x8 r;
#pragma unroll
  for (int j = 0; j < 8; ++j) r[j] = (__bf16)acc[j];
  *(bf16x8*)&comb[((size_t)n * HW + y * 64 + xq) * 256 + (h << 5) + (cg << 3)] = r;
}

// ---------------------------------------------------------------------------
extern "C" void kernel_launch(void* const* d_in, const int* in_sizes, int n_in,
                              void* d_out, int out_size, void* d_ws,
                              size_t ws_size, hipStream_t stream)
{
  const float* x      = (const float*)d_in[0];
  // d_in[1] = Wq, d_in[2] = Wk : dead code (q,k unused in reference)
  const float* Wv     = (const float*)d_in[3];
  const float* off_w  = (const float*)d_in[4];
  const float* off_b  = (const float*)d_in[5];
  const float* attn_w = (const float*)d_in[6];
  const float* attn_b = (const float*)d_in[7];
  const float* Wo     = (const float*)d_in[8];
  float* out = (float*)d_out;

  __bf16* vtb   = (__bf16*)d_ws;                         // 16.78 MB
  __bf16* xp    = vtb + (size_t)N_ * HW * OUT_;          // 16.78 MB
  __bf16* comb  = xp + (size_t)N_ * HW * C_;             // 16.78 MB
  __bf16* P2    = comb + (size_t)N_ * HW * OUT_;         // 16.78 MB (head-packed)
  __bf16* Wp    = P2 + (size_t)N_ * HW * 256;            //  1.18 MB (256 rows)
  __bf16* Wvb   = Wp + (size_t)WPROWS * KTOT;            //  128 KB
  __bf16* Wob   = Wvb + (size_t)OUT_ * C_;               //  128 KB
  __bf16* zbuf  = Wob + (size_t)OUT_ * OUT_;             //  4 KB zero page
  float*  biasp = (float*)(zbuf + 2048);                 //  1 KB

  pack_w_kernel<<<dim3(256), 256, 0, stream>>>(off_w, off_b, attn_w, attn_b,
                                               Wp, biasp, zbuf);
  pack_mat_kernel<<<dim3(256), 256, 0, stream>>>(Wv, Wvb);
  pack_mat_kernel<<<dim3(256), 256, 0, stream>>>(Wo, Wob);
  pack_x_kernel<<<dim3(4, 64, N_), 256, 0, stream>>>(x, xp);
  conv_mfma_kernel<<<dim3(32, 2, N_), 256, 0, stream>>>(xp, Wp, biasp, zbuf, P2);
  gemm256_kernel<0><<<dim3(32, 2, N_), 256, 0, stream>>>(xp, Wvb, vtb, nullptr);
  sample_kernel<<<dim3(N_ * HEADS * H_), 256, 0, stream>>>(vtb, P2, comb);
  gemm256_kernel<1><<<dim3(32, 2, N_), 256, 0, stream>>>(comb, Wob, nullptr,
                                                         out);
}

// Round 22
// 117.574 us; speedup vs baseline: 1.2196x; 1.0581x over previous
//
#include <hip/hip_runtime.h>
#include <math.h>

#define N_    8
#define C_    256
#define H_    64
#define W_    64
#define HW    4096
#define OUT_  256
#define HEADS 8
#define HD    32
#define K2    9
#define OFFCH 144   // HEADS*K2*2
#define AWCH  72    // HEADS*K2
#define KTOT  2304  // 9 taps * 256 c
#define WPROWS 256  // Wp rows (216 real + zero pad to 256)
#define ABASE 16896 // bf16 offset of B region in conv smem (2*4*66*32)

typedef __bf16 bf16x8 __attribute__((ext_vector_type(8)));
typedef __bf16 bf16x4 __attribute__((ext_vector_type(4)));
typedef float  f32x4  __attribute__((ext_vector_type(4)));

__device__ __forceinline__ void gload_lds16(const void* g, void* l) {
  __builtin_amdgcn_global_load_lds(
      (const __attribute__((address_space(1))) void*)g,
      (__attribute__((address_space(3))) void*)l, 16, 0, 0);
}

// ---------------------------------------------------------------------------
// pack_x: fp32 NCHW -> bf16 NHWC  (xp[n][y][x][c]), LDS 64x64 tile transpose.
// ---------------------------------------------------------------------------
__global__ __launch_bounds__(256) void pack_x_kernel(
    const float* __restrict__ x, __bf16* __restrict__ xp)
{
  const int c0 = blockIdx.x << 6;
  const int y  = blockIdx.y;
  const int n  = blockIdx.z;
  const int tid = threadIdx.x;
  __shared__ float tile[64][65];

  const int tx = tid & 63, tg = tid >> 6;
#pragma unroll
  for (int i = 0; i < 16; ++i) {
    int cl = tg + (i << 2);
    tile[cl][tx] = x[((size_t)(n * C_ + c0 + cl) * H_ + y) * W_ + tx];
  }
  __syncthreads();
#pragma unroll
  for (int i = 0; i < 16; ++i) {
    int xl = tg + (i << 2);
    xp[((size_t)(n * HW) + y * W_ + xl) * C_ + c0 + tx] = (__bf16)tile[tx][xl];
  }
}

// ---------------------------------------------------------------------------
// pack_w: conv weights -> bf16 Wp[256][tap][c] (tap-major K, rows 216+ zero),
// + bias, + zero page for halo DMA.
// ---------------------------------------------------------------------------
__global__ __launch_bounds__(256) void pack_w_kernel(
    const float* __restrict__ off_w, const float* __restrict__ off_b,
    const float* __restrict__ attn_w, const float* __restrict__ attn_b,
    __bf16* __restrict__ Wp, float* __restrict__ biasp,
    __bf16* __restrict__ zbuf)
{
  const int co = blockIdx.x;
  const int c  = threadIdx.x;
  if (co == 0) {  // zero page for OOB halo DMA (4096 B)
    *(uint4*)&zbuf[(size_t)c * 8] = make_uint4(0u, 0u, 0u, 0u);
  }
  const float* base = nullptr;
  if (co < OFFCH)      base = off_w  + ((size_t)co * C_ + c) * 9;
  else if (co < 216)   base = attn_w + ((size_t)(co - OFFCH) * C_ + c) * 9;
#pragma unroll
  for (int t = 0; t < 9; ++t) {
    float w = base ? base[t] : 0.f;
    Wp[(size_t)co * KTOT + t * C_ + c] = (__bf16)w;
  }
  if (c == 0) {
    float b = 0.f;
    if (co < OFFCH) b = off_b[co];
    else if (co < 216) b = attn_b[co - OFFCH];
    biasp[co] = b;
  }
}

// 256x256 fp32 -> bf16 row-major
__global__ __launch_bounds__(256) void pack_mat_kernel(
    const float* __restrict__ Wsrc, __bf16* __restrict__ Wdst)
{
  const int i = blockIdx.x * 256 + threadIdx.x;
  Wdst[i] = (__bf16)Wsrc[i];
}

// ---------------------------------------------------------------------------
// conv_mfma R21 (unchanged): wave-private B (3 bufs, 2 ahead), hoisted
// addresses, 18-tap unrolled body, counted vmcnt, per-slice barrier.
// ---------------------------------------------------------------------------
__global__ __launch_bounds__(256) void conv_mfma_kernel(
    const __bf16* __restrict__ xp, const __bf16* __restrict__ Wp,
    const float* __restrict__ biasp, const __bf16* __restrict__ zbuf,
    __bf16* __restrict__ P2)
{
  const int yt = blockIdx.x;
  const int bn = blockIdx.y;
  const int n  = blockIdx.z;
  const int y0 = yt << 1;
  const int tid = threadIdx.x;
  const int lw = tid & 63, wv = tid >> 6;
  const int lr = lw & 15, lg = lw >> 4;

  __shared__ __align__(16) __bf16 smem[16896 + 12288];

  f32x4 acc[8][2];
#pragma unroll
  for (int m = 0; m < 8; ++m)
#pragma unroll
    for (int nt = 0; nt < 2; ++nt) acc[m][nt] = (f32x4){0.f, 0.f, 0.f, 0.f};

  if (tid < 64) {
    int p = tid & 3, cs = (tid >> 2) & 1, r = (tid >> 3) & 3, buf = tid >> 5;
    int col = cs ? 65 : 0;
    *(uint4*)&smem[((buf * 4 + r) * 66 + col) * 32 + p * 8] =
        make_uint4(0u, 0u, 0u, 0u);
  }

  int aoff[3][4];
#pragma unroll
  for (int d = 0; d < 3; ++d)
#pragma unroll
    for (int mm = 0; mm < 4; ++mm) {
      int col = (mm << 4) + lr + d;
      int p = lg ^ ((col >> 1) & 3);
      aoff[d][mm] = col * 32 + p * 8;
    }
  int boff[2];
#pragma unroll
  for (int nt = 0; nt < 2; ++nt) {
    int col = (nt << 4) + lr;
    int p = lg ^ ((col >> 1) & 3);
    boff[nt] = ABASE + wv * 3072 + col * 32 + p * 8;
  }

  const int scg = lw & 3;
  const __bf16* gB[2];
#pragma unroll
  for (int jj = 0; jj < 2; ++jj) {
    int col = (jj << 4) + (lw >> 2);
    int cg = scg ^ ((col >> 1) & 3);
    gB[jj] = Wp + (size_t)(bn * 128 + wv * 32 + col) * KTOT + (cg << 3);
  }
  const __bf16* gA[4];
  int aAdd;
  {
    int y = y0 - 1 + wv;
    bool valid = ((unsigned)y < (unsigned)H_);
    aAdd = valid ? 1 : 0;
#pragma unroll
    for (int k = 0; k < 4; ++k) {
      int col = 1 + (k << 4) + (lw >> 2);
      int cg = scg ^ ((col >> 1) & 3);
      gA[k] = valid
          ? xp + ((size_t)(n * HW) + y * W_ + (col - 1)) * C_ + (cg << 3)
          : zbuf;
    }
  }

  auto stageB = [&](int elemOff, int pbuf) {
#pragma unroll
    for (int jj = 0; jj < 2; ++jj)
      gload_lds16(gB[jj] + elemOff,
                  &smem[ABASE + wv * 3072 + pbuf * 1024 + (jj << 9)]);
  };
  auto stageA = [&](int c0elem, int buf) {
    const int add = aAdd ? c0elem : 0;
#pragma unroll
    for (int k = 0; k < 4; ++k)
      gload_lds16(gA[k] + add,
                  &smem[((buf * 4 + wv) * 66 + 1 + (k << 4)) * 32]);
  };

  stageA(0, 0);
  stageB(0 * C_ + 0, 0);
  stageB(1 * C_ + 0, 1);
  asm volatile("s_waitcnt vmcnt(4)" ::: "memory");
  __builtin_amdgcn_s_barrier();
  asm volatile("" ::: "memory");

  for (int cc = 0; cc < 4; ++cc) {
    const bool lastcc = (cc == 3);
#pragma unroll
    for (int sub = 0; sub < 2; ++sub) {
      const int ci = (cc << 1) + sub;
      const int abuf = sub;
#pragma unroll
      for (int tt = 0; tt < 9; ++tt) {
        const int dy = tt / 3, dxp = tt - dy * 3;
        const int pbR = tt % 3;
        const int pbW = (tt + 2) % 3;
        const bool lastSlice = lastcc && (sub == 1);

        if (tt == 1 && ci < 7) stageA((ci + 1) << 5, sub ^ 1);

        if (!(lastSlice && tt >= 7)) {
          const int tn  = (tt < 7) ? (tt + 2) : (tt - 7);
          const int cin = (tt < 7) ? ci : (ci + 1);
          stageB(tn * C_ + (cin << 5), pbW);
        }

        if (lastSlice && tt == 8)
          asm volatile("s_waitcnt vmcnt(0)" ::: "memory");
        else if (lastSlice && tt == 7)
          asm volatile("s_waitcnt vmcnt(2)" ::: "memory");
        else if ((tt == 1 || tt == 2) && ci < 7)
          asm volatile("s_waitcnt vmcnt(8)" ::: "memory");
        else
          asm volatile("s_waitcnt vmcnt(4)" ::: "memory");

        bf16x8 a[8], b[2];
#pragma unroll
        for (int m = 0; m < 8; ++m) {
          const int rr = (m >> 2) + dy;
          a[m] = *(const bf16x8*)&smem[aoff[dxp][m & 3] +
                                       (abuf * 4 + rr) * 2112];
        }
#pragma unroll
        for (int nt = 0; nt < 2; ++nt)
          b[nt] = *(const bf16x8*)&smem[boff[nt] + (pbR << 10)];

        __builtin_amdgcn_s_setprio(1);
#pragma unroll
        for (int m = 0; m < 8; ++m)
#pragma unroll
          for (int nt = 0; nt < 2; ++nt)
            acc[m][nt] = __builtin_amdgcn_mfma_f32_16x16x32_bf16(
                a[m], b[nt], acc[m][nt], 0, 0, 0);
        __builtin_amdgcn_s_setprio(0);

        if (tt == 8 && !lastSlice) {
          __builtin_amdgcn_s_barrier();
          asm volatile("" ::: "memory");
        }
      }
    }
  }

#pragma unroll
  for (int nt = 0; nt < 2; ++nt) {
    const int co = bn * 128 + wv * 32 + (nt << 4) + lr;
    if (co < 216) {
      const float bias = biasp[co];
      int idx;
      if (co < OFFCH) {
        int hh = co / 18;
        idx = (hh << 5) + (co - 18 * hh);
      } else {
        int r = co - OFFCH;
        int hh = r / 9;
        idx = (hh << 5) + 18 + (r - 9 * hh);
      }
#pragma unroll
      for (int m = 0; m < 8; ++m) {
#pragma unroll
        for (int reg = 0; reg < 4; ++reg) {
          const int sl = (m << 4) + (lg << 2) + reg;
          const int yout = y0 + (sl >> 6), xo = sl & 63;
          float v = acc[m][nt][reg] + bias;
          if (co >= OFFCH) v = 1.f / (1.f + expf(-v));
          P2[((size_t)n * HW + yout * W_ + xo) * 256 + idx] = (__bf16)v;
        }
      }
    }
  }
}

// ---------------------------------------------------------------------------
// gemm256 R22: conv-proven pipeline. 3 rotating A/B buf pairs staged 2 slices
// ahead via gload_lds (chunk-XOR src swizzle -> conflict-free ds_read_b128),
// fully unrolled K (8 slices), 1 barrier + counted vmcnt per slice, setprio.
// Stage(k+2) issued AFTER slice-k barrier: buf (k+2)%3 was last read in slice
// k-1 whose reads completed pre-barrier -> race-free. LDS 48 KB -> 3 blk/CU.
// MODE 0: bf16 NHWC out (vproj). MODE 1: fp32 NCHW out (wo).
// ---------------------------------------------------------------------------
template <int MODE>
__global__ __launch_bounds__(256) void gemm256_kernel(
    const __bf16* __restrict__ A, const __bf16* __restrict__ Wb,
    __bf16* __restrict__ out_b, float* __restrict__ out_f)
{
  const int st = blockIdx.x;
  const int bn = blockIdx.y;
  const int n  = blockIdx.z;
  const int s0 = st << 7;
  const int tid = threadIdx.x;
  const int lw = tid & 63, wv = tid >> 6;
  const int lr = lw & 15, lg = lw >> 4;
  const int sm_base = wv << 5;

  // A bufs at 0,4096,8192; B bufs at 12288+{0,4096,8192}  (elems; 48 KB)
  __shared__ __align__(16) __bf16 smem[24576];

  f32x4 acc[2][8];
#pragma unroll
  for (int m = 0; m < 2; ++m)
#pragma unroll
    for (int nt = 0; nt < 8; ++nt) acc[m][nt] = (f32x4){0.f, 0.f, 0.f, 0.f};

  // hoisted LDS read offsets (buf-0 base; +buf*4096)
  int aoff[2];
#pragma unroll
  for (int m = 0; m < 2; ++m) {
    int row = sm_base + (m << 4) + lr;
    int p = lg ^ ((row >> 1) & 3);
    aoff[m] = row * 32 + p * 8;
  }
  int boff[8];
#pragma unroll
  for (int nt = 0; nt < 8; ++nt) {
    int row = (nt << 4) + lr;
    int p = lg ^ ((row >> 1) & 3);
    boff[nt] = 12288 + row * 32 + p * 8;
  }

  // hoisted global source pointers (lane stages rows j*16+(lw>>2), j=wv*2+jj)
  const __bf16* gA[2];
  const __bf16* gB[2];
#pragma unroll
  for (int jj = 0; jj < 2; ++jj) {
    int j = wv * 2 + jj;
    int row = (j << 4) + (lw >> 2);
    int cg = (lw & 3) ^ ((row >> 1) & 3);
    gA[jj] = A + ((size_t)n * HW + s0 + row) * 256 + (cg << 3);
    gB[jj] = Wb + ((size_t)((bn << 7) + row)) * 256 + (cg << 3);
  }

  auto stage = [&](int k, int buf) {
    const int koff = k << 5;
#pragma unroll
    for (int jj = 0; jj < 2; ++jj)
      gload_lds16(gA[jj] + koff, &smem[buf * 4096 + ((wv * 2 + jj) << 9)]);
#pragma unroll
    for (int jj = 0; jj < 2; ++jj)
      gload_lds16(gB[jj] + koff,
                  &smem[12288 + buf * 4096 + ((wv * 2 + jj) << 9)]);
  };

  // prologue: slices 0,1 in flight
  stage(0, 0);
  stage(1, 1);

#pragma unroll
  for (int k = 0; k < 8; ++k) {
    if (k < 7)
      asm volatile("s_waitcnt vmcnt(4)" ::: "memory");   // stage(k) done
    else
      asm volatile("s_waitcnt vmcnt(0)" ::: "memory");
    __builtin_amdgcn_s_barrier();
    asm volatile("" ::: "memory");

    if (k + 2 < 8) stage(k + 2, (k + 2) % 3);

    const int buf = k % 3;
    bf16x8 a[2], b[8];
#pragma unroll
    for (int m = 0; m < 2; ++m)
      a[m] = *(const bf16x8*)&smem[aoff[m] + buf * 4096];
#pragma unroll
    for (int nt = 0; nt < 8; ++nt)
      b[nt] = *(const bf16x8*)&smem[boff[nt] + buf * 4096];

    __builtin_amdgcn_s_setprio(1);
#pragma unroll
    for (int m = 0; m < 2; ++m)
#pragma unroll
      for (int nt = 0; nt < 8; ++nt)
        acc[m][nt] = __builtin_amdgcn_mfma_f32_16x16x32_bf16(
            a[m], b[nt], acc[m][nt], 0, 0, 0);
    __builtin_amdgcn_s_setprio(0);
  }

#pragma unroll
  for (int m = 0; m < 2; ++m) {
#pragma unroll
    for (int nt = 0; nt < 8; ++nt) {
      const int co = (bn << 7) + (nt << 4) + lr;
      if (MODE == 0) {
#pragma unroll
        for (int reg = 0; reg < 4; ++reg) {
          const int sm = sm_base + (m << 4) + (lg << 2) + reg;
          out_b[((size_t)n * HW + s0 + sm) * 256 + co] = (__bf16)acc[m][nt][reg];
        }
      } else {
        const int sm = sm_base + (m << 4) + (lg << 2);
        float4 v4 = make_float4(acc[m][nt][0], acc[m][nt][1],
                                acc[m][nt][2], acc[m][nt][3]);
        *(float4*)&out_f[((size_t)(n * 256 + co)) * HW + s0 + sm] = v4;
      }
    }
  }
}

// ---------------------------------------------------------------------------
// Deformable sampling R18 (unchanged): LDS-windowed gather.
// ---------------------------------------------------------------------------
__global__ __launch_bounds__(256) void sample_kernel(
    const __bf16* __restrict__ vtb, const __bf16* __restrict__ P2,
    __bf16* __restrict__ comb)
{
  const int b = blockIdx.x;           // (n*8 + h)*64 + y
  const int y = b & 63;
  const int h = (b >> 6) & 7;
  const int n = b >> 9;
  const int tid = threadIdx.x;
  const int xq = tid >> 2, cg = tid & 3;
  const int lw = tid & 63, wv = tid >> 6;

  __shared__ __align__(16) __bf16 vsl[8 * 64 * 32];   // [r][x][cho] 32 KB

  const int xs = (wv << 4) + (lw >> 2);
  const int cs = lw & 3;
  const __bf16* vrow0 =
      vtb + ((size_t)n * HW) * 256 + (h << 5) + (cs << 3) + (size_t)xs * 256;
#pragma unroll
  for (int r = 0; r < 8; ++r) {
    int yy = y - 3 + r;
    if ((unsigned)yy < (unsigned)H_)            // block-uniform branch
      gload_lds16(vrow0 + (size_t)yy * (64 * 256),
                  &vsl[(r * 64 + (wv << 4)) * 32]);
  }

  const __bf16* prow = P2 + ((size_t)n * HW + y * 64 + xq) * 256 + (h << 5);
  bf16x8 p0 = *(const bf16x8*)(prow);
  bf16x8 p1 = *(const bf16x8*)(prow + 8);
  bf16x8 p2 = *(const bf16x8*)(prow + 16);
  bf16x4 p3 = *(const bf16x4*)(prow + 24);

  __syncthreads();                               // drains vmcnt (gload_lds)

  float acc[8];
#pragma unroll
  for (int j = 0; j < 8; ++j) acc[j] = 0.f;

  const __bf16* vbase = vtb + ((size_t)n * HW) * 256 + (h << 5) + (cg << 3);

#pragma unroll
  for (int k = 0; k < K2; ++k) {
    float offx, offy, a;
    if (k < 4)      { offx = (float)p0[2 * k];       offy = (float)p0[2 * k + 1]; }
    else if (k < 8) { offx = (float)p1[2 * (k - 4)]; offy = (float)p1[2 * (k - 4) + 1]; }
    else            { offx = (float)p2[0];           offy = (float)p2[1]; }
    if (k < 6)      a = (float)p2[2 + k];
    else            a = (float)p3[k - 6];

    const float xpf = (float)xq + offx * (63.f / 64.f);
    const float ypf = (float)y  + offy * (63.f / 64.f);
    const float fx0 = floorf(xpf), fy0 = floorf(ypf);
    const int x0 = (int)fx0, y0 = (int)fy0;
    const float wx1 = xpf - fx0, wx0 = 1.f - wx1;
    const float wy1 = ypf - fy0, wy0 = 1.f - wy1;

#pragma unroll
    for (int cy = 0; cy < 2; ++cy) {
      const int yi = y0 + cy;
      if ((unsigned)yi >= (unsigned)H_) continue;
      const float wy = cy ? wy1 : wy0;
      const int ridx = yi - (y - 3);
#pragma unroll
      for (int cx = 0; cx < 2; ++cx) {
        const int xi = x0 + cx;
        if ((unsigned)xi >= (unsigned)W_) continue;
        const float cw = a * wy * (cx ? wx1 : wx0);
        bf16x8 v;
        if ((unsigned)ridx < 8u) {               // in-window: LDS
          v = *(const bf16x8*)&vsl[(ridx * 64 + xi) * 32 + (cg << 3)];
        } else {                                 // rare escape: global
          v = *(const bf16x8*)(vbase + (size_t)(yi * W_ + xi) * 256);
        }
#pragma unroll
        for (int j = 0; j < 8; ++j) acc[j] = fmaf(cw, (float)v[j], acc[j]);
      }
    }
  }

  bf16x8 r;
#pragma unroll
  for (int j = 0; j < 8; ++j) r[j] = (__bf16)acc[j];
  *(bf16x8*)&comb[((size_t)n * HW + y * 64 + xq) * 256 + (h << 5) + (cg << 3)] = r;
}

// ---------------------------------------------------------------------------
extern "C" void kernel_launch(void* const* d_in, const int* in_sizes, int n_in,
                              void* d_out, int out_size, void* d_ws,
                              size_t ws_size, hipStream_t stream)
{
  const float* x      = (const float*)d_in[0];
  // d_in[1] = Wq, d_in[2] = Wk : dead code (q,k unused in reference)
  const float* Wv     = (const float*)d_in[3];
  const float* off_w  = (const float*)d_in[4];
  const float* off_b  = (const float*)d_in[5];
  const float* attn_w = (const float*)d_in[6];
  const float* attn_b = (const float*)d_in[7];
  const float* Wo     = (const float*)d_in[8];
  float* out = (float*)d_out;

  __bf16* vtb   = (__bf16*)d_ws;                         // 16.78 MB
  __bf16* xp    = vtb + (size_t)N_ * HW * OUT_;          // 16.78 MB
  __bf16* comb  = xp + (size_t)N_ * HW * C_;             // 16.78 MB
  __bf16* P2    = comb + (size_t)N_ * HW * OUT_;         // 16.78 MB (head-packed)
  __bf16* Wp    = P2 + (size_t)N_ * HW * 256;            //  1.18 MB (256 rows)
  __bf16* Wvb   = Wp + (size_t)WPROWS * KTOT;            //  128 KB
  __bf16* Wob   = Wvb + (size_t)OUT_ * C_;               //  128 KB
  __bf16* zbuf  = Wob + (size_t)OUT_ * OUT_;             //  4 KB zero page
  float*  biasp = (float*)(zbuf + 2048);                 //  1 KB

  pack_w_kernel<<<dim3(256), 256, 0, stream>>>(off_w, off_b, attn_w, attn_b,
                                               Wp, biasp, zbuf);
  pack_mat_kernel<<<dim3(256), 256, 0, stream>>>(Wv, Wvb);
  pack_mat_kernel<<<dim3(256), 256, 0, stream>>>(Wo, Wob);
  pack_x_kernel<<<dim3(4, 64, N_), 256, 0, stream>>>(x, xp);
  conv_mfma_kernel<<<dim3(32, 2, N_), 256, 0, stream>>>(xp, Wp, biasp, zbuf, P2);
  gemm256_kernel<0><<<dim3(32, 2, N_), 256, 0, stream>>>(xp, Wvb, vtb, nullptr);
  sample_kernel<<<dim3(N_ * HEADS * H_), 256, 0, stream>>>(vtb, P2, comb);
  gemm256_kernel<1><<<dim3(32, 2, N_), 256, 0, stream>>>(comb, Wob, nullptr,
                                                         out);
}